// Round 1
// baseline (5573.583 us; speedup 1.0000x reference)
//
#include <hip/hip_runtime.h>
#include <cmath>

#define NN 100000
#define NE 3200000
#define TT 2048
#define MM 256
#define STR 16   // padded row stride (floats) for 10-wide node arrays -> 64B rows

__device__ __forceinline__ void atomicMaxF(float* addr, float v) {
    if (v >= 0.f) atomicMax((int*)addr, __float_as_int(v));
    else          atomicMin((unsigned int*)addr, __float_as_uint(v));
}

// ---------------- init small buffers ----------------
__global__ void init_small_kernel(float* amax, float* den_m, float* num_m, float* Vsum) {
    int m = threadIdx.x;
    if (m < MM) { amax[m] = -INFINITY; den_m[m] = 0.f; num_m[m] = 0.f; }
    if (m == 0) Vsum[0] = 0.f;
}

// ---------------- per-layer: compute xl, xr; zero acc, den ----------------
__global__ __launch_bounds__(256) void prep_kernel(
    const float* __restrict__ hprev,   // [NN,STR] (first 10 cols valid) or nullptr
    const float* __restrict__ x1,      // [NN,15]
    const float* __restrict__ Wl, const float* __restrict__ bl,
    const float* __restrict__ Wr, const float* __restrict__ br,
    float* __restrict__ xl, float* __restrict__ xr,
    float* __restrict__ acc, float* __restrict__ den,
    int din)                           // 15 or 25
{
    __shared__ float sWl[250], sWr[250], sbl[10], sbr[10];
    int tid = threadIdx.x;
    int nw = 10 * din;
    for (int i = tid; i < nw; i += blockDim.x) { sWl[i] = Wl[i]; sWr[i] = Wr[i]; }
    if (tid < 10) { sbl[tid] = bl[tid]; sbr[tid] = br[tid]; }
    __syncthreads();
    int n = blockIdx.x * blockDim.x + tid;
    if (n >= NN) return;

    float in[25];
    if (din == 15) {
        #pragma unroll
        for (int k = 0; k < 15; k++) in[k] = x1[n * 15 + k];
    } else {
        #pragma unroll
        for (int k = 0; k < 10; k++) in[k] = hprev[n * STR + k];
        #pragma unroll
        for (int k = 0; k < 15; k++) in[10 + k] = x1[n * 15 + k];
    }

    float4 z = make_float4(0.f, 0.f, 0.f, 0.f);
    float4* accr = (float4*)(acc + n * STR);
    accr[0] = z; accr[1] = z; accr[2] = z; accr[3] = z;
    den[n] = 0.f;

    #pragma unroll
    for (int j = 0; j < 10; j++) {
        float sl = sbl[j], sr = sbr[j];
        for (int k = 0; k < din; k++) {
            sl += in[k] * sWl[j * din + k];
            sr += in[k] * sWr[j * din + k];
        }
        xl[n * STR + j] = sl;
        xr[n * STR + j] = sr;
    }
}

// ---------------- per-layer: single edge pass (no segment-max: softmax is shift-invariant) ----
__global__ __launch_bounds__(256) void edge_kernel(
    const int* __restrict__ src, const int* __restrict__ dst,
    const float* __restrict__ xl, const float* __restrict__ xr,
    const float* __restrict__ att,
    float* __restrict__ acc, float* __restrict__ den)
{
    int i = blockIdx.x * blockDim.x + threadIdx.x;
    if (i >= NE) return;
    int s = src[i], d = dst[i];
    const float* xls = xl + s * STR;
    const float* xrd = xr + d * STR;
    float4 v0 = *(const float4*)(xls);
    float4 v1 = *(const float4*)(xls + 4);
    float2 v2 = *(const float2*)(xls + 8);
    float4 w0 = *(const float4*)(xrd);
    float4 w1 = *(const float4*)(xrd + 4);
    float2 w2 = *(const float2*)(xrd + 8);
    float a[10] = {v0.x, v0.y, v0.z, v0.w, v1.x, v1.y, v1.z, v1.w, v2.x, v2.y};
    float b[10] = {w0.x, w0.y, w0.z, w0.w, w1.x, w1.y, w1.z, w1.w, w2.x, w2.y};
    float e = 0.f;
    #pragma unroll
    for (int k = 0; k < 10; k++) {
        float t = a[k] + b[k];
        t = t > 0.f ? t : 0.2f * t;
        e += att[k] * t;
    }
    float ex = __expf(e);
    atomicAdd(den + d, ex);
    float* ad = acc + d * STR;
    #pragma unroll
    for (int k = 0; k < 10; k++) atomicAdd(ad + k, ex * a[k]);
}

// ---------------- per-layer: fold in self-loop, normalize, bias, relu ----------------
__global__ __launch_bounds__(256) void finalize_kernel(
    const float* __restrict__ xl, const float* __restrict__ xr,
    const float* __restrict__ att, const float* __restrict__ acc,
    const float* __restrict__ den, const float* __restrict__ bias,
    float* __restrict__ hout)
{
    int n = blockIdx.x * blockDim.x + threadIdx.x;
    if (n >= NN) return;
    const float* xln = xl + n * STR;
    const float* xrn = xr + n * STR;
    float a[10], b[10];
    #pragma unroll
    for (int k = 0; k < 10; k++) { a[k] = xln[k]; b[k] = xrn[k]; }
    float e = 0.f;
    #pragma unroll
    for (int k = 0; k < 10; k++) {
        float t = a[k] + b[k];
        t = t > 0.f ? t : 0.2f * t;
        e += att[k] * t;
    }
    float ex = __expf(e);
    float inv = 1.f / (den[n] + ex);
    #pragma unroll
    for (int k = 0; k < 10; k++) {
        float v = (acc[n * STR + k] + ex * a[k]) * inv + bias[k];
        hout[n * STR + k] = v > 0.f ? v : 0.f;
    }
}

// ---------------- value head: V = tanh(mean(relu([x,x1,x2]@linW^T+linb)@lin2W^T+lin2b)) ------
__global__ __launch_bounds__(256) void value_kernel(
    const float* __restrict__ x, const float* __restrict__ x1, const float* __restrict__ x2,
    const float* __restrict__ lin_W, const float* __restrict__ lin_b,
    const float* __restrict__ lin2_W, const float* __restrict__ lin2_b,
    float* __restrict__ Vsum)
{
    __shared__ float sW[15 * 29], sb[15], sW2[15];
    __shared__ float red[256];
    int tid = threadIdx.x;
    for (int i = tid; i < 15 * 29; i += 256) sW[i] = lin_W[i];
    if (tid < 15) { sb[tid] = lin_b[tid]; sW2[tid] = lin2_W[tid]; }
    __syncthreads();
    int n = blockIdx.x * 256 + tid;
    float local = 0.f;
    if (n < NN) {
        float in[29];
        #pragma unroll
        for (int k = 0; k < 10; k++) in[k] = x[n * STR + k];
        #pragma unroll
        for (int k = 0; k < 15; k++) in[10 + k] = x1[n * 15 + k];
        #pragma unroll
        for (int k = 0; k < 4; k++) in[25 + k] = x2[k];
        float sc = lin2_b[0];
        #pragma unroll
        for (int j = 0; j < 15; j++) {
            float s = sb[j];
            for (int k = 0; k < 29; k++) s += in[k] * sW[j * 29 + k];
            sc += (s > 0.f ? s : 0.f) * sW2[j];
        }
        local = sc;
    }
    red[tid] = local;
    __syncthreads();
    for (int off = 128; off > 0; off >>= 1) {
        if (tid < off) red[tid] += red[tid + off];
        __syncthreads();
    }
    if (tid == 0) atomicAdd(Vsum, red[0]);
}

// ---------------- order head, stage 1: per-order al/pi + segment max ----------------
__global__ __launch_bounds__(256) void orders_kernel(
    const float* __restrict__ x, const float* __restrict__ x1,
    const int* __restrict__ move_type, const int* __restrict__ m_src,
    const int* __restrict__ m_dst, const int* __restrict__ m_target,
    const float* __restrict__ m_armies, const int* __restrict__ move_id,
    const float* __restrict__ aaa_W, const float* __restrict__ aaa_b,
    const float* __restrict__ ccc_W, const float* __restrict__ ccc_b,
    const float* __restrict__ attl_W, const float* __restrict__ attl_b,
    const float* __restrict__ pi_W, const float* __restrict__ pi_b,
    float* __restrict__ al_out, float* __restrict__ pi_out, float* __restrict__ amax)
{
    __shared__ float sA[20 * 48], sC[20 * 23], sAb[20], sCb[20];
    int tid = threadIdx.x;
    for (int i = tid; i < 20 * 48; i += 256) sA[i] = aaa_W[i];
    for (int i = tid; i < 20 * 23; i += 256) sC[i] = ccc_W[i];
    if (tid < 20) { sAb[tid] = aaa_b[tid]; sCb[tid] = ccc_b[tid]; }
    __syncthreads();
    int t = blockIdx.x * 256 + tid;
    if (t >= TT) return;

    float armies = m_armies[t];
    float hm[20];
    if (move_type[t] == 0) {
        int sn = m_src[t], dn = m_dst[t];
        float f[48];
        #pragma unroll
        for (int k = 0; k < 10; k++) f[k] = x[sn * STR + k];
        #pragma unroll
        for (int k = 0; k < 10; k++) f[10 + k] = x[dn * STR + k];
        #pragma unroll
        for (int k = 0; k < 12; k++) f[20 + k] = x1[sn * 15 + 3 + k];
        #pragma unroll
        for (int k = 0; k < 14; k++) f[32 + k] = x1[dn * 15 + 1 + k];
        f[46] = armies;
        f[47] = 0.6f * armies - 0.7f * (x1[dn * 15 + 3] + x1[dn * 15 + 4]);
        #pragma unroll
        for (int j = 0; j < 20; j++) {
            float s = sAb[j];
            for (int k = 0; k < 48; k++) s += f[k] * sA[j * 48 + k];
            hm[j] = s > 0.f ? s : 0.f;
        }
    } else {
        int tg = m_target[t];
        float f[23];
        #pragma unroll
        for (int k = 0; k < 10; k++) f[k] = x[tg * STR + k];
        #pragma unroll
        for (int k = 0; k < 12; k++) f[10 + k] = x1[tg * 15 + 3 + k];
        f[22] = armies;
        #pragma unroll
        for (int j = 0; j < 20; j++) {
            float s = sCb[j];
            for (int k = 0; k < 23; k++) s += f[k] * sC[j * 23 + k];
            hm[j] = s > 0.f ? s : 0.f;
        }
    }
    float a = attl_b[0], p = pi_b[0];
    #pragma unroll
    for (int j = 0; j < 20; j++) { a += hm[j] * attl_W[j]; p += hm[j] * pi_W[j]; }
    al_out[t] = a;
    pi_out[t] = p;
    atomicMaxF(&amax[move_id[t]], a);
}

// ---------------- order head, stage 2: segment exp-sums ----------------
__global__ __launch_bounds__(256) void orders2_kernel(
    const float* __restrict__ al, const float* __restrict__ piv,
    const int* __restrict__ move_id, const float* __restrict__ amax,
    float* __restrict__ den_m, float* __restrict__ num_m)
{
    int t = blockIdx.x * 256 + threadIdx.x;
    if (t >= TT) return;
    int m = move_id[t];
    float ex = __expf(al[t] - amax[m]);
    atomicAdd(den_m + m, ex);
    atomicAdd(num_m + m, ex * piv[t]);
}

// ---------------- final: p -> log_softmax, V -> tanh(mean) ----------------
__global__ __launch_bounds__(256) void final_kernel(
    const float* __restrict__ num_m, const float* __restrict__ den_m,
    const float* __restrict__ Vsum, float* __restrict__ out)
{
    __shared__ float sh[256];
    __shared__ float s_max, s_sum;
    int m = threadIdx.x;
    float p = num_m[m] / den_m[m];
    sh[m] = p;
    __syncthreads();
    for (int off = 128; off > 0; off >>= 1) {
        if (m < off) sh[m] = fmaxf(sh[m], sh[m + off]);
        __syncthreads();
    }
    if (m == 0) s_max = sh[0];
    __syncthreads();
    float e = __expf(p - s_max);
    sh[m] = e;
    __syncthreads();
    for (int off = 128; off > 0; off >>= 1) {
        if (m < off) sh[m] += sh[m + off];
        __syncthreads();
    }
    if (m == 0) s_sum = sh[0];
    __syncthreads();
    out[1 + m] = p - s_max - logf(s_sum);
    if (m == 0) out[0] = tanhf(Vsum[0] / (float)NN);
}

extern "C" void kernel_launch(void* const* d_in, const int* in_sizes, int n_in,
                              void* d_out, int out_size, void* d_ws, size_t ws_size,
                              hipStream_t stream) {
    const float* x1        = (const float*)d_in[0];
    const float* x2        = (const float*)d_in[1];
    const int*   esrc      = (const int*)d_in[2];
    const int*   edst      = (const int*)d_in[3];
    const int*   move_type = (const int*)d_in[4];
    const int*   m_src     = (const int*)d_in[5];
    const int*   m_dst     = (const int*)d_in[6];
    const int*   m_target  = (const int*)d_in[7];
    const float* m_armies  = (const float*)d_in[8];
    const int*   move_id   = (const int*)d_in[9];
    const float* W[3][6];
    for (int l = 0; l < 3; l++)
        for (int j = 0; j < 6; j++)
            W[l][j] = (const float*)d_in[10 + l * 6 + j];
    const float* lin_W  = (const float*)d_in[28];
    const float* lin_b  = (const float*)d_in[29];
    const float* lin2_W = (const float*)d_in[30];
    const float* lin2_b = (const float*)d_in[31];
    const float* aaa_W  = (const float*)d_in[32];
    const float* aaa_b  = (const float*)d_in[33];
    const float* ccc_W  = (const float*)d_in[34];
    const float* ccc_b  = (const float*)d_in[35];
    const float* attl_W = (const float*)d_in[36];
    const float* attl_b = (const float*)d_in[37];
    const float* pi_W   = (const float*)d_in[38];
    const float* pi_b   = (const float*)d_in[39];

    float* ws = (float*)d_ws;
    float* xl    = ws; ws += NN * STR;
    float* xr    = ws; ws += NN * STR;
    float* acc   = ws; ws += NN * STR;
    float* hA    = ws; ws += NN * STR;
    float* hB    = ws; ws += NN * STR;
    float* den   = ws; ws += NN;
    float* al    = ws; ws += TT;
    float* piv   = ws; ws += TT;
    float* amax  = ws; ws += MM;
    float* den_m = ws; ws += MM;
    float* num_m = ws; ws += MM;
    float* Vsum  = ws; ws += 1;

    dim3 blk(256);
    dim3 gN((NN + 255) / 256);
    dim3 gE((NE + 255) / 256);
    dim3 gT(TT / 256);

    init_small_kernel<<<dim3(1), blk, 0, stream>>>(amax, den_m, num_m, Vsum);

    // layer 1 (din=15, input x1)
    prep_kernel<<<gN, blk, 0, stream>>>(nullptr, x1, W[0][0], W[0][1], W[0][2], W[0][3],
                                        xl, xr, acc, den, 15);
    edge_kernel<<<gE, blk, 0, stream>>>(esrc, edst, xl, xr, W[0][4], acc, den);
    finalize_kernel<<<gN, blk, 0, stream>>>(xl, xr, W[0][4], acc, den, W[0][5], hA);

    // layer 2 (din=25, input [hA, x1])
    prep_kernel<<<gN, blk, 0, stream>>>(hA, x1, W[1][0], W[1][1], W[1][2], W[1][3],
                                        xl, xr, acc, den, 25);
    edge_kernel<<<gE, blk, 0, stream>>>(esrc, edst, xl, xr, W[1][4], acc, den);
    finalize_kernel<<<gN, blk, 0, stream>>>(xl, xr, W[1][4], acc, den, W[1][5], hB);

    // layer 3 (din=25, input [hB, x1])
    prep_kernel<<<gN, blk, 0, stream>>>(hB, x1, W[2][0], W[2][1], W[2][2], W[2][3],
                                        xl, xr, acc, den, 25);
    edge_kernel<<<gE, blk, 0, stream>>>(esrc, edst, xl, xr, W[2][4], acc, den);
    finalize_kernel<<<gN, blk, 0, stream>>>(xl, xr, W[2][4], acc, den, W[2][5], hA);

    // heads
    value_kernel<<<gN, blk, 0, stream>>>(hA, x1, x2, lin_W, lin_b, lin2_W, lin2_b, Vsum);
    orders_kernel<<<gT, blk, 0, stream>>>(hA, x1, move_type, m_src, m_dst, m_target,
                                          m_armies, move_id, aaa_W, aaa_b, ccc_W, ccc_b,
                                          attl_W, attl_b, pi_W, pi_b, al, piv, amax);
    orders2_kernel<<<gT, blk, 0, stream>>>(al, piv, move_id, amax, den_m, num_m);
    final_kernel<<<dim3(1), blk, 0, stream>>>(num_m, den_m, Vsum, (float*)d_out);
}

// Round 2
// 1093.908 us; speedup vs baseline: 5.0951x; 5.0951x over previous
//
#include <hip/hip_runtime.h>
#include <cmath>

#define NN 100000
#define NE 3200000
#define TT 2048
#define MM 256
#define STR 16   // padded row stride (floats) for 10-wide node arrays -> 64B rows

__device__ __forceinline__ void atomicMaxF(float* addr, float v) {
    if (v >= 0.f) atomicMax((int*)addr, __float_as_int(v));
    else          atomicMin((unsigned int*)addr, __float_as_uint(v));
}

// ---------------- init: zero counts + small buffers ----------------
__global__ __launch_bounds__(256) void init_kernel(int* counts, float* amax, float* den_m,
                                                   float* num_m, float* Vsum) {
    int i = blockIdx.x * 256 + threadIdx.x;
    if (i < NN) counts[i] = 0;
    if (i < MM) { amax[i] = -INFINITY; den_m[i] = 0.f; num_m[i] = 0.f; }
    if (i == 0) Vsum[0] = 0.f;
}

// ---------------- counting sort, pass 1: histogram of dst ----------------
__global__ __launch_bounds__(256) void hist_kernel(const int* __restrict__ dst, int* __restrict__ counts) {
    int i = blockIdx.x * 256 + threadIdx.x;
    if (i < NE) atomicAdd(&counts[dst[i]], 1);
}

// ---------------- counting sort, pass 2: exclusive scan (single block, 1024 thr) ----------
__global__ __launch_bounds__(1024) void scan_kernel(const int* __restrict__ counts,
                                                    int* __restrict__ start,
                                                    int* __restrict__ cursor) {
    __shared__ int ssum[1024];
    int tid = threadIdx.x;
    const int per = (NN + 1023) / 1024;  // 98
    int base = tid * per;
    int s = 0;
    for (int i = 0; i < per; i++) {
        int idx = base + i;
        if (idx < NN) s += counts[idx];
    }
    ssum[tid] = s;
    __syncthreads();
    // Hillis-Steele inclusive scan over 1024
    for (int off = 1; off < 1024; off <<= 1) {
        int v = (tid >= off) ? ssum[tid - off] : 0;
        __syncthreads();
        ssum[tid] += v;
        __syncthreads();
    }
    int run = ssum[tid] - s;  // exclusive base for this thread's range
    for (int i = 0; i < per; i++) {
        int idx = base + i;
        if (idx < NN) {
            start[idx] = run;
            cursor[idx] = run;
            run += counts[idx];
        }
    }
    if (tid == 0) start[NN] = NE;
}

// ---------------- counting sort, pass 3: scatter src into dst-sorted order ----------
__global__ __launch_bounds__(256) void scatter_kernel(const int* __restrict__ src,
                                                      const int* __restrict__ dst,
                                                      int* __restrict__ cursor,
                                                      int* __restrict__ srt_src) {
    int i = blockIdx.x * 256 + threadIdx.x;
    if (i >= NE) return;
    int d = dst[i];
    int pos = atomicAdd(&cursor[d], 1);
    srt_src[pos] = src[i];
}

// ---------------- per-layer: compute xl, xr ----------------
__global__ __launch_bounds__(256) void prep_kernel(
    const float* __restrict__ hprev,   // [NN,STR] (first 10 cols valid) or nullptr
    const float* __restrict__ x1,      // [NN,15]
    const float* __restrict__ Wl, const float* __restrict__ bl,
    const float* __restrict__ Wr, const float* __restrict__ br,
    float* __restrict__ xl, float* __restrict__ xr,
    int din)                           // 15 or 25
{
    __shared__ float sWl[250], sWr[250], sbl[10], sbr[10];
    int tid = threadIdx.x;
    int nw = 10 * din;
    for (int i = tid; i < nw; i += blockDim.x) { sWl[i] = Wl[i]; sWr[i] = Wr[i]; }
    if (tid < 10) { sbl[tid] = bl[tid]; sbr[tid] = br[tid]; }
    __syncthreads();
    int n = blockIdx.x * blockDim.x + tid;
    if (n >= NN) return;

    float in[25];
    if (din == 15) {
        #pragma unroll
        for (int k = 0; k < 15; k++) in[k] = x1[n * 15 + k];
    } else {
        #pragma unroll
        for (int k = 0; k < 10; k++) in[k] = hprev[n * STR + k];
        #pragma unroll
        for (int k = 0; k < 15; k++) in[10 + k] = x1[n * 15 + k];
    }

    #pragma unroll
    for (int j = 0; j < 10; j++) {
        float sl = sbl[j], sr = sbr[j];
        for (int k = 0; k < din; k++) {
            sl += in[k] * sWl[j * din + k];
            sr += in[k] * sWr[j * din + k];
        }
        xl[n * STR + j] = sl;
        xr[n * STR + j] = sr;
    }
}

// ---------------- per-layer: CSR gather pass (no atomics; softmax shift-invariant) --------
// One thread per dst node: accumulate den/acc over in-edges in registers,
// fold self-loop, normalize, bias, relu, write h once.
__global__ __launch_bounds__(256) void gather_kernel(
    const int* __restrict__ srt_src, const int* __restrict__ start,
    const float* __restrict__ xl, const float* __restrict__ xr,
    const float* __restrict__ att, const float* __restrict__ bias,
    float* __restrict__ hout)
{
    int n = blockIdx.x * 256 + threadIdx.x;
    if (n >= NN) return;

    float at[10];
    #pragma unroll
    for (int k = 0; k < 10; k++) at[k] = att[k];

    // self row
    const float* xln = xl + n * STR;
    const float* xrn = xr + n * STR;
    float b[10], aself[10];
    #pragma unroll
    for (int k = 0; k < 10; k++) { aself[k] = xln[k]; b[k] = xrn[k]; }
    float e = 0.f;
    #pragma unroll
    for (int k = 0; k < 10; k++) {
        float t = aself[k] + b[k];
        t = t > 0.f ? t : 0.2f * t;
        e += at[k] * t;
    }
    float ex = __expf(e);
    float den = ex;
    float acc[10];
    #pragma unroll
    for (int k = 0; k < 10; k++) acc[k] = ex * aself[k];

    int i0 = start[n], i1 = start[n + 1];
    for (int i = i0; i < i1; i++) {
        int s = srt_src[i];
        const float* xls = xl + s * STR;
        float4 v0 = *(const float4*)(xls);
        float4 v1 = *(const float4*)(xls + 4);
        float2 v2 = *(const float2*)(xls + 8);
        float a[10] = {v0.x, v0.y, v0.z, v0.w, v1.x, v1.y, v1.z, v1.w, v2.x, v2.y};
        float ee = 0.f;
        #pragma unroll
        for (int k = 0; k < 10; k++) {
            float t = a[k] + b[k];
            t = t > 0.f ? t : 0.2f * t;
            ee += at[k] * t;
        }
        float exe = __expf(ee);
        den += exe;
        #pragma unroll
        for (int k = 0; k < 10; k++) acc[k] += exe * a[k];
    }

    float inv = 1.f / den;
    #pragma unroll
    for (int k = 0; k < 10; k++) {
        float v = acc[k] * inv + bias[k];
        hout[n * STR + k] = v > 0.f ? v : 0.f;
    }
}

// ---------------- value head ----------------
__global__ __launch_bounds__(256) void value_kernel(
    const float* __restrict__ x, const float* __restrict__ x1, const float* __restrict__ x2,
    const float* __restrict__ lin_W, const float* __restrict__ lin_b,
    const float* __restrict__ lin2_W, const float* __restrict__ lin2_b,
    float* __restrict__ Vsum)
{
    __shared__ float sW[15 * 29], sb[15], sW2[15];
    __shared__ float red[256];
    int tid = threadIdx.x;
    for (int i = tid; i < 15 * 29; i += 256) sW[i] = lin_W[i];
    if (tid < 15) { sb[tid] = lin_b[tid]; sW2[tid] = lin2_W[tid]; }
    __syncthreads();
    int n = blockIdx.x * 256 + tid;
    float local = 0.f;
    if (n < NN) {
        float in[29];
        #pragma unroll
        for (int k = 0; k < 10; k++) in[k] = x[n * STR + k];
        #pragma unroll
        for (int k = 0; k < 15; k++) in[10 + k] = x1[n * 15 + k];
        #pragma unroll
        for (int k = 0; k < 4; k++) in[25 + k] = x2[k];
        float sc = lin2_b[0];
        #pragma unroll
        for (int j = 0; j < 15; j++) {
            float s = sb[j];
            for (int k = 0; k < 29; k++) s += in[k] * sW[j * 29 + k];
            sc += (s > 0.f ? s : 0.f) * sW2[j];
        }
        local = sc;
    }
    red[tid] = local;
    __syncthreads();
    for (int off = 128; off > 0; off >>= 1) {
        if (tid < off) red[tid] += red[tid + off];
        __syncthreads();
    }
    if (tid == 0) atomicAdd(Vsum, red[0]);
}

// ---------------- order head, stage 1 ----------------
__global__ __launch_bounds__(256) void orders_kernel(
    const float* __restrict__ x, const float* __restrict__ x1,
    const int* __restrict__ move_type, const int* __restrict__ m_src,
    const int* __restrict__ m_dst, const int* __restrict__ m_target,
    const float* __restrict__ m_armies, const int* __restrict__ move_id,
    const float* __restrict__ aaa_W, const float* __restrict__ aaa_b,
    const float* __restrict__ ccc_W, const float* __restrict__ ccc_b,
    const float* __restrict__ attl_W, const float* __restrict__ attl_b,
    const float* __restrict__ pi_W, const float* __restrict__ pi_b,
    float* __restrict__ al_out, float* __restrict__ pi_out, float* __restrict__ amax)
{
    __shared__ float sA[20 * 48], sC[20 * 23], sAb[20], sCb[20];
    int tid = threadIdx.x;
    for (int i = tid; i < 20 * 48; i += 256) sA[i] = aaa_W[i];
    for (int i = tid; i < 20 * 23; i += 256) sC[i] = ccc_W[i];
    if (tid < 20) { sAb[tid] = aaa_b[tid]; sCb[tid] = ccc_b[tid]; }
    __syncthreads();
    int t = blockIdx.x * 256 + tid;
    if (t >= TT) return;

    float armies = m_armies[t];
    float hm[20];
    if (move_type[t] == 0) {
        int sn = m_src[t], dn = m_dst[t];
        float f[48];
        #pragma unroll
        for (int k = 0; k < 10; k++) f[k] = x[sn * STR + k];
        #pragma unroll
        for (int k = 0; k < 10; k++) f[10 + k] = x[dn * STR + k];
        #pragma unroll
        for (int k = 0; k < 12; k++) f[20 + k] = x1[sn * 15 + 3 + k];
        #pragma unroll
        for (int k = 0; k < 14; k++) f[32 + k] = x1[dn * 15 + 1 + k];
        f[46] = armies;
        f[47] = 0.6f * armies - 0.7f * (x1[dn * 15 + 3] + x1[dn * 15 + 4]);
        #pragma unroll
        for (int j = 0; j < 20; j++) {
            float s = sAb[j];
            for (int k = 0; k < 48; k++) s += f[k] * sA[j * 48 + k];
            hm[j] = s > 0.f ? s : 0.f;
        }
    } else {
        int tg = m_target[t];
        float f[23];
        #pragma unroll
        for (int k = 0; k < 10; k++) f[k] = x[tg * STR + k];
        #pragma unroll
        for (int k = 0; k < 12; k++) f[10 + k] = x1[tg * 15 + 3 + k];
        f[22] = armies;
        #pragma unroll
        for (int j = 0; j < 20; j++) {
            float s = sCb[j];
            for (int k = 0; k < 23; k++) s += f[k] * sC[j * 23 + k];
            hm[j] = s > 0.f ? s : 0.f;
        }
    }
    float a = attl_b[0], p = pi_b[0];
    #pragma unroll
    for (int j = 0; j < 20; j++) { a += hm[j] * attl_W[j]; p += hm[j] * pi_W[j]; }
    al_out[t] = a;
    pi_out[t] = p;
    atomicMaxF(&amax[move_id[t]], a);
}

// ---------------- order head, stage 2 ----------------
__global__ __launch_bounds__(256) void orders2_kernel(
    const float* __restrict__ al, const float* __restrict__ piv,
    const int* __restrict__ move_id, const float* __restrict__ amax,
    float* __restrict__ den_m, float* __restrict__ num_m)
{
    int t = blockIdx.x * 256 + threadIdx.x;
    if (t >= TT) return;
    int m = move_id[t];
    float ex = __expf(al[t] - amax[m]);
    atomicAdd(den_m + m, ex);
    atomicAdd(num_m + m, ex * piv[t]);
}

// ---------------- final: p -> log_softmax, V -> tanh(mean) ----------------
__global__ __launch_bounds__(256) void final_kernel(
    const float* __restrict__ num_m, const float* __restrict__ den_m,
    const float* __restrict__ Vsum, float* __restrict__ out)
{
    __shared__ float sh[256];
    __shared__ float s_max, s_sum;
    int m = threadIdx.x;
    float p = num_m[m] / den_m[m];
    sh[m] = p;
    __syncthreads();
    for (int off = 128; off > 0; off >>= 1) {
        if (m < off) sh[m] = fmaxf(sh[m], sh[m + off]);
        __syncthreads();
    }
    if (m == 0) s_max = sh[0];
    __syncthreads();
    float e = __expf(p - s_max);
    sh[m] = e;
    __syncthreads();
    for (int off = 128; off > 0; off >>= 1) {
        if (m < off) sh[m] += sh[m + off];
        __syncthreads();
    }
    if (m == 0) s_sum = sh[0];
    __syncthreads();
    out[1 + m] = p - s_max - logf(s_sum);
    if (m == 0) out[0] = tanhf(Vsum[0] / (float)NN);
}

extern "C" void kernel_launch(void* const* d_in, const int* in_sizes, int n_in,
                              void* d_out, int out_size, void* d_ws, size_t ws_size,
                              hipStream_t stream) {
    const float* x1        = (const float*)d_in[0];
    const float* x2        = (const float*)d_in[1];
    const int*   esrc      = (const int*)d_in[2];
    const int*   edst      = (const int*)d_in[3];
    const int*   move_type = (const int*)d_in[4];
    const int*   m_src     = (const int*)d_in[5];
    const int*   m_dst     = (const int*)d_in[6];
    const int*   m_target  = (const int*)d_in[7];
    const float* m_armies  = (const float*)d_in[8];
    const int*   move_id   = (const int*)d_in[9];
    const float* W[3][6];
    for (int l = 0; l < 3; l++)
        for (int j = 0; j < 6; j++)
            W[l][j] = (const float*)d_in[10 + l * 6 + j];
    const float* lin_W  = (const float*)d_in[28];
    const float* lin_b  = (const float*)d_in[29];
    const float* lin2_W = (const float*)d_in[30];
    const float* lin2_b = (const float*)d_in[31];
    const float* aaa_W  = (const float*)d_in[32];
    const float* aaa_b  = (const float*)d_in[33];
    const float* ccc_W  = (const float*)d_in[34];
    const float* ccc_b  = (const float*)d_in[35];
    const float* attl_W = (const float*)d_in[36];
    const float* attl_b = (const float*)d_in[37];
    const float* pi_W   = (const float*)d_in[38];
    const float* pi_b   = (const float*)d_in[39];

    // workspace layout (~33 MB)
    float* ws = (float*)d_ws;
    float* xl    = ws; ws += NN * STR;
    float* xr    = ws; ws += NN * STR;
    float* hA    = ws; ws += NN * STR;
    float* al    = ws; ws += TT;
    float* piv   = ws; ws += TT;
    float* amax  = ws; ws += MM;
    float* den_m = ws; ws += MM;
    float* num_m = ws; ws += MM;
    float* Vsum  = ws; ws += 1;
    int* iws = (int*)ws;
    int* counts  = iws; iws += NN;
    int* startv  = iws; iws += NN + 1;
    int* cursor  = iws; iws += NN;
    int* srt_src = iws; iws += NE;

    dim3 blk(256);
    dim3 gN((NN + 255) / 256);
    dim3 gE((NE + 255) / 256);
    dim3 gT(TT / 256);

    // build dst-sorted CSR once; reused by all 3 layers
    init_kernel<<<gN, blk, 0, stream>>>(counts, amax, den_m, num_m, Vsum);
    hist_kernel<<<gE, blk, 0, stream>>>(edst, counts);
    scan_kernel<<<dim3(1), dim3(1024), 0, stream>>>(counts, startv, cursor);
    scatter_kernel<<<gE, blk, 0, stream>>>(esrc, edst, cursor, srt_src);

    // layer 1 (din=15, input x1)
    prep_kernel<<<gN, blk, 0, stream>>>(nullptr, x1, W[0][0], W[0][1], W[0][2], W[0][3], xl, xr, 15);
    gather_kernel<<<gN, blk, 0, stream>>>(srt_src, startv, xl, xr, W[0][4], W[0][5], hA);

    // layer 2 (din=25, input [hA, x1]) — hA consumed by prep before being overwritten
    prep_kernel<<<gN, blk, 0, stream>>>(hA, x1, W[1][0], W[1][1], W[1][2], W[1][3], xl, xr, 25);
    gather_kernel<<<gN, blk, 0, stream>>>(srt_src, startv, xl, xr, W[1][4], W[1][5], hA);

    // layer 3 (din=25, input [hA, x1])
    prep_kernel<<<gN, blk, 0, stream>>>(hA, x1, W[2][0], W[2][1], W[2][2], W[2][3], xl, xr, 25);
    gather_kernel<<<gN, blk, 0, stream>>>(srt_src, startv, xl, xr, W[2][4], W[2][5], hA);

    // heads
    value_kernel<<<gN, blk, 0, stream>>>(hA, x1, x2, lin_W, lin_b, lin2_W, lin2_b, Vsum);
    orders_kernel<<<gT, blk, 0, stream>>>(hA, x1, move_type, m_src, m_dst, m_target,
                                          m_armies, move_id, aaa_W, aaa_b, ccc_W, ccc_b,
                                          attl_W, attl_b, pi_W, pi_b, al, piv, amax);
    orders2_kernel<<<gT, blk, 0, stream>>>(al, piv, move_id, amax, den_m, num_m);
    final_kernel<<<dim3(1), blk, 0, stream>>>(num_m, den_m, Vsum, (float*)d_out);
}

// Round 3
// 1041.028 us; speedup vs baseline: 5.3539x; 1.0508x over previous
//
#include <hip/hip_runtime.h>
#include <cmath>

#define NN 100000
#define NE 3200000
#define TT 2048
#define MM 256
#define STR 16    // padded row stride (floats) for 10-wide node arrays -> 64B rows
#define BSZ 128   // nodes per bucket
#define NB 782    // ceil(NN/BSZ)
#define EPB 8192  // edges per scatter/hist block
#define NBLK 391  // ceil(NE/EPB)

__device__ __forceinline__ void atomicMaxF(float* addr, float v) {
    if (v >= 0.f) atomicMax((int*)addr, __float_as_int(v));
    else          atomicMin((unsigned int*)addr, __float_as_uint(v));
}

// ---------------- init: zero bucket counts + small buffers ----------------
__global__ __launch_bounds__(1024) void init_kernel(int* bcounts, float* amax, float* den_m,
                                                    float* num_m, float* Vsum) {
    int i = threadIdx.x;
    if (i < NB) bcounts[i] = 0;
    if (i < MM) { amax[i] = -INFINITY; den_m[i] = 0.f; num_m[i] = 0.f; }
    if (i == 0) Vsum[0] = 0.f;
}

// ---------------- bucket histogram (LDS pre-aggregated) ----------------
__global__ __launch_bounds__(256) void hist_kernel(const int* __restrict__ dst,
                                                   int* __restrict__ bcounts) {
    __shared__ int h[NB];
    int tid = threadIdx.x;
    for (int i = tid; i < NB; i += 256) h[i] = 0;
    __syncthreads();
    int base = blockIdx.x * EPB;
    int end = base + EPB; if (end > NE) end = NE;
    for (int i = base + tid; i < end; i += 256) atomicAdd(&h[dst[i] >> 7], 1);
    __syncthreads();
    for (int i = tid; i < NB; i += 256) { int n = h[i]; if (n) atomicAdd(&bcounts[i], n); }
}

// ---------------- exclusive scan over NB buckets (single block) ----------------
__global__ __launch_bounds__(1024) void scan_kernel(const int* __restrict__ bcounts,
                                                    int* __restrict__ bstart,
                                                    int* __restrict__ bcursor) {
    __shared__ int s[1024];
    int tid = threadIdx.x;
    int v = (tid < NB) ? bcounts[tid] : 0;
    s[tid] = v;
    __syncthreads();
    for (int off = 1; off < 1024; off <<= 1) {
        int t = (tid >= off) ? s[tid - off] : 0;
        __syncthreads();
        s[tid] += t;
        __syncthreads();
    }
    if (tid < NB) { int excl = s[tid] - v; bstart[tid] = excl; bcursor[tid] = excl; }
    if (tid == 0) bstart[NB] = NE;
}

// ---------------- scatter: block-aggregated reservations, packed (local_dst,src) -------
__global__ __launch_bounds__(256) void scatter_kernel(const int* __restrict__ src,
                                                      const int* __restrict__ dst,
                                                      int* __restrict__ bcursor,
                                                      int* __restrict__ srt) {
    __shared__ int h[NB];   // local count -> global base
    __shared__ int c[NB];   // local running cursor
    int tid = threadIdx.x;
    for (int i = tid; i < NB; i += 256) h[i] = 0;
    __syncthreads();
    int base = blockIdx.x * EPB;
    int end = base + EPB; if (end > NE) end = NE;
    for (int i = base + tid; i < end; i += 256) atomicAdd(&h[dst[i] >> 7], 1);
    __syncthreads();
    for (int i = tid; i < NB; i += 256) {
        int n = h[i];
        h[i] = n ? atomicAdd(&bcursor[i], n) : 0;
        c[i] = 0;
    }
    __syncthreads();
    for (int i = base + tid; i < end; i += 256) {
        int d = dst[i];
        int b = d >> 7;
        int off = atomicAdd(&c[b], 1);
        srt[h[b] + off] = ((d & 127) << 17) | src[i];
    }
}

// ---------------- per-layer: compute xl, xr ----------------
__global__ __launch_bounds__(256) void prep_kernel(
    const float* __restrict__ hprev,   // [NN,STR] (first 10 cols valid) or nullptr
    const float* __restrict__ x1,      // [NN,15]
    const float* __restrict__ Wl, const float* __restrict__ bl,
    const float* __restrict__ Wr, const float* __restrict__ br,
    float* __restrict__ xl, float* __restrict__ xr,
    int din)                           // 15 or 25
{
    __shared__ float sWl[250], sWr[250], sbl[10], sbr[10];
    int tid = threadIdx.x;
    int nw = 10 * din;
    for (int i = tid; i < nw; i += blockDim.x) { sWl[i] = Wl[i]; sWr[i] = Wr[i]; }
    if (tid < 10) { sbl[tid] = bl[tid]; sbr[tid] = br[tid]; }
    __syncthreads();
    int n = blockIdx.x * blockDim.x + tid;
    if (n >= NN) return;

    float in[25];
    if (din == 15) {
        #pragma unroll
        for (int k = 0; k < 15; k++) in[k] = x1[n * 15 + k];
    } else {
        #pragma unroll
        for (int k = 0; k < 10; k++) in[k] = hprev[n * STR + k];
        #pragma unroll
        for (int k = 0; k < 15; k++) in[10 + k] = x1[n * 15 + k];
    }

    #pragma unroll
    for (int j = 0; j < 10; j++) {
        float sl = sbl[j], sr = sbr[j];
        for (int k = 0; k < din; k++) {
            sl += in[k] * sWl[j * din + k];
            sr += in[k] * sWr[j * din + k];
        }
        xl[n * STR + j] = sl;
        xr[n * STR + j] = sr;
    }
}

// ---------------- per-layer: bucket gather, edge-parallel, LDS accumulators ----------
// One block per bucket of 128 dst nodes. accs stride 11 (odd -> bank spread).
__global__ __launch_bounds__(256) void gather_kernel(
    const int* __restrict__ srt, const int* __restrict__ bstart,
    const float* __restrict__ xl, const float* __restrict__ xr,
    const float* __restrict__ att, const float* __restrict__ bias,
    float* __restrict__ hout)
{
    __shared__ float accs[BSZ * 11];  // [local_dst][0..9]=acc, [10]=den
    __shared__ float xrs[BSZ * 10];
    __shared__ float sat[10];
    int b = blockIdx.x, tid = threadIdx.x;
    if (tid < 10) sat[tid] = att[tid];
    __syncthreads();

    int n0 = b * BSZ;
    if (tid < BSZ) {
        int n = n0 + tid;
        if (n < NN) {
            const float* xln = xl + n * STR;
            const float* xrn = xr + n * STR;
            float a[10], r[10];
            #pragma unroll
            for (int k = 0; k < 10; k++) { a[k] = xln[k]; r[k] = xrn[k]; }
            #pragma unroll
            for (int k = 0; k < 10; k++) xrs[tid * 10 + k] = r[k];
            float e = 0.f;
            #pragma unroll
            for (int k = 0; k < 10; k++) {
                float t = a[k] + r[k];
                t = t > 0.f ? t : 0.2f * t;
                e += sat[k] * t;
            }
            float ex = __expf(e);
            #pragma unroll
            for (int k = 0; k < 10; k++) accs[tid * 11 + k] = ex * a[k];
            accs[tid * 11 + 10] = ex;
        } else {
            #pragma unroll
            for (int k = 0; k < 11; k++) accs[tid * 11 + k] = 0.f;
        }
    }
    __syncthreads();

    int i0 = bstart[b], i1 = bstart[b + 1];
    for (int i = i0 + tid; i < i1; i += 256) {
        int p = srt[i];
        int s = p & 0x1FFFF;
        int ld = p >> 17;
        const float* xls = xl + s * STR;
        float4 v0 = *(const float4*)(xls);
        float4 v1 = *(const float4*)(xls + 4);
        float2 v2 = *(const float2*)(xls + 8);
        float a[10] = {v0.x, v0.y, v0.z, v0.w, v1.x, v1.y, v1.z, v1.w, v2.x, v2.y};
        const float* r = xrs + ld * 10;
        float e = 0.f;
        #pragma unroll
        for (int k = 0; k < 10; k++) {
            float t = a[k] + r[k];
            t = t > 0.f ? t : 0.2f * t;
            e += sat[k] * t;
        }
        float ex = __expf(e);
        float* ac = accs + ld * 11;
        #pragma unroll
        for (int k = 0; k < 10; k++) atomicAdd(ac + k, ex * a[k]);
        atomicAdd(ac + 10, ex);
    }
    __syncthreads();

    if (tid < BSZ) {
        int n = n0 + tid;
        if (n < NN) {
            float inv = 1.f / accs[tid * 11 + 10];
            #pragma unroll
            for (int k = 0; k < 10; k++) {
                float v = accs[tid * 11 + k] * inv + bias[k];
                hout[n * STR + k] = v > 0.f ? v : 0.f;
            }
        }
    }
}

// ---------------- value head ----------------
__global__ __launch_bounds__(256) void value_kernel(
    const float* __restrict__ x, const float* __restrict__ x1, const float* __restrict__ x2,
    const float* __restrict__ lin_W, const float* __restrict__ lin_b,
    const float* __restrict__ lin2_W, const float* __restrict__ lin2_b,
    float* __restrict__ Vsum)
{
    __shared__ float sW[15 * 29], sb[15], sW2[15];
    __shared__ float red[256];
    int tid = threadIdx.x;
    for (int i = tid; i < 15 * 29; i += 256) sW[i] = lin_W[i];
    if (tid < 15) { sb[tid] = lin_b[tid]; sW2[tid] = lin2_W[tid]; }
    __syncthreads();
    int n = blockIdx.x * 256 + tid;
    float local = 0.f;
    if (n < NN) {
        float in[29];
        #pragma unroll
        for (int k = 0; k < 10; k++) in[k] = x[n * STR + k];
        #pragma unroll
        for (int k = 0; k < 15; k++) in[10 + k] = x1[n * 15 + k];
        #pragma unroll
        for (int k = 0; k < 4; k++) in[25 + k] = x2[k];
        float sc = lin2_b[0];
        #pragma unroll
        for (int j = 0; j < 15; j++) {
            float s = sb[j];
            for (int k = 0; k < 29; k++) s += in[k] * sW[j * 29 + k];
            sc += (s > 0.f ? s : 0.f) * sW2[j];
        }
        local = sc;
    }
    red[tid] = local;
    __syncthreads();
    for (int off = 128; off > 0; off >>= 1) {
        if (tid < off) red[tid] += red[tid + off];
        __syncthreads();
    }
    if (tid == 0) atomicAdd(Vsum, red[0]);
}

// ---------------- order head, stage 1 ----------------
__global__ __launch_bounds__(256) void orders_kernel(
    const float* __restrict__ x, const float* __restrict__ x1,
    const int* __restrict__ move_type, const int* __restrict__ m_src,
    const int* __restrict__ m_dst, const int* __restrict__ m_target,
    const float* __restrict__ m_armies, const int* __restrict__ move_id,
    const float* __restrict__ aaa_W, const float* __restrict__ aaa_b,
    const float* __restrict__ ccc_W, const float* __restrict__ ccc_b,
    const float* __restrict__ attl_W, const float* __restrict__ attl_b,
    const float* __restrict__ pi_W, const float* __restrict__ pi_b,
    float* __restrict__ al_out, float* __restrict__ pi_out, float* __restrict__ amax)
{
    __shared__ float sA[20 * 48], sC[20 * 23], sAb[20], sCb[20];
    int tid = threadIdx.x;
    for (int i = tid; i < 20 * 48; i += 256) sA[i] = aaa_W[i];
    for (int i = tid; i < 20 * 23; i += 256) sC[i] = ccc_W[i];
    if (tid < 20) { sAb[tid] = aaa_b[tid]; sCb[tid] = ccc_b[tid]; }
    __syncthreads();
    int t = blockIdx.x * 256 + tid;
    if (t >= TT) return;

    float armies = m_armies[t];
    float hm[20];
    if (move_type[t] == 0) {
        int sn = m_src[t], dn = m_dst[t];
        float f[48];
        #pragma unroll
        for (int k = 0; k < 10; k++) f[k] = x[sn * STR + k];
        #pragma unroll
        for (int k = 0; k < 10; k++) f[10 + k] = x[dn * STR + k];
        #pragma unroll
        for (int k = 0; k < 12; k++) f[20 + k] = x1[sn * 15 + 3 + k];
        #pragma unroll
        for (int k = 0; k < 14; k++) f[32 + k] = x1[dn * 15 + 1 + k];
        f[46] = armies;
        f[47] = 0.6f * armies - 0.7f * (x1[dn * 15 + 3] + x1[dn * 15 + 4]);
        #pragma unroll
        for (int j = 0; j < 20; j++) {
            float s = sAb[j];
            for (int k = 0; k < 48; k++) s += f[k] * sA[j * 48 + k];
            hm[j] = s > 0.f ? s : 0.f;
        }
    } else {
        int tg = m_target[t];
        float f[23];
        #pragma unroll
        for (int k = 0; k < 10; k++) f[k] = x[tg * STR + k];
        #pragma unroll
        for (int k = 0; k < 12; k++) f[10 + k] = x1[tg * 15 + 3 + k];
        f[22] = armies;
        #pragma unroll
        for (int j = 0; j < 20; j++) {
            float s = sCb[j];
            for (int k = 0; k < 23; k++) s += f[k] * sC[j * 23 + k];
            hm[j] = s > 0.f ? s : 0.f;
        }
    }
    float a = attl_b[0], p = pi_b[0];
    #pragma unroll
    for (int j = 0; j < 20; j++) { a += hm[j] * attl_W[j]; p += hm[j] * pi_W[j]; }
    al_out[t] = a;
    pi_out[t] = p;
    atomicMaxF(&amax[move_id[t]], a);
}

// ---------------- order head, stage 2 ----------------
__global__ __launch_bounds__(256) void orders2_kernel(
    const float* __restrict__ al, const float* __restrict__ piv,
    const int* __restrict__ move_id, const float* __restrict__ amax,
    float* __restrict__ den_m, float* __restrict__ num_m)
{
    int t = blockIdx.x * 256 + threadIdx.x;
    if (t >= TT) return;
    int m = move_id[t];
    float ex = __expf(al[t] - amax[m]);
    atomicAdd(den_m + m, ex);
    atomicAdd(num_m + m, ex * piv[t]);
}

// ---------------- final: p -> log_softmax, V -> tanh(mean) ----------------
__global__ __launch_bounds__(256) void final_kernel(
    const float* __restrict__ num_m, const float* __restrict__ den_m,
    const float* __restrict__ Vsum, float* __restrict__ out)
{
    __shared__ float sh[256];
    __shared__ float s_max, s_sum;
    int m = threadIdx.x;
    float p = num_m[m] / den_m[m];
    sh[m] = p;
    __syncthreads();
    for (int off = 128; off > 0; off >>= 1) {
        if (m < off) sh[m] = fmaxf(sh[m], sh[m + off]);
        __syncthreads();
    }
    if (m == 0) s_max = sh[0];
    __syncthreads();
    float e = __expf(p - s_max);
    sh[m] = e;
    __syncthreads();
    for (int off = 128; off > 0; off >>= 1) {
        if (m < off) sh[m] += sh[m + off];
        __syncthreads();
    }
    if (m == 0) s_sum = sh[0];
    __syncthreads();
    out[1 + m] = p - s_max - logf(s_sum);
    if (m == 0) out[0] = tanhf(Vsum[0] / (float)NN);
}

extern "C" void kernel_launch(void* const* d_in, const int* in_sizes, int n_in,
                              void* d_out, int out_size, void* d_ws, size_t ws_size,
                              hipStream_t stream) {
    const float* x1        = (const float*)d_in[0];
    const float* x2        = (const float*)d_in[1];
    const int*   esrc      = (const int*)d_in[2];
    const int*   edst      = (const int*)d_in[3];
    const int*   move_type = (const int*)d_in[4];
    const int*   m_src     = (const int*)d_in[5];
    const int*   m_dst     = (const int*)d_in[6];
    const int*   m_target  = (const int*)d_in[7];
    const float* m_armies  = (const float*)d_in[8];
    const int*   move_id   = (const int*)d_in[9];
    const float* W[3][6];
    for (int l = 0; l < 3; l++)
        for (int j = 0; j < 6; j++)
            W[l][j] = (const float*)d_in[10 + l * 6 + j];
    const float* lin_W  = (const float*)d_in[28];
    const float* lin_b  = (const float*)d_in[29];
    const float* lin2_W = (const float*)d_in[30];
    const float* lin2_b = (const float*)d_in[31];
    const float* aaa_W  = (const float*)d_in[32];
    const float* aaa_b  = (const float*)d_in[33];
    const float* ccc_W  = (const float*)d_in[34];
    const float* ccc_b  = (const float*)d_in[35];
    const float* attl_W = (const float*)d_in[36];
    const float* attl_b = (const float*)d_in[37];
    const float* pi_W   = (const float*)d_in[38];
    const float* pi_b   = (const float*)d_in[39];

    // workspace layout (~33 MB)
    float* ws = (float*)d_ws;
    float* xl    = ws; ws += NN * STR;
    float* xr    = ws; ws += NN * STR;
    float* hA    = ws; ws += NN * STR;
    float* al    = ws; ws += TT;
    float* piv   = ws; ws += TT;
    float* amax  = ws; ws += MM;
    float* den_m = ws; ws += MM;
    float* num_m = ws; ws += MM;
    float* Vsum  = ws; ws += 1;
    int* iws = (int*)ws;
    int* bcounts = iws; iws += NB;
    int* bstart  = iws; iws += NB + 1;
    int* bcursor = iws; iws += NB;
    int* srt     = iws; iws += NE;

    dim3 blk(256);
    dim3 gN((NN + 255) / 256);
    dim3 gT(TT / 256);

    // build bucketed CSR once; reused by all 3 layers
    init_kernel<<<dim3(1), dim3(1024), 0, stream>>>(bcounts, amax, den_m, num_m, Vsum);
    hist_kernel<<<dim3(NBLK), blk, 0, stream>>>(edst, bcounts);
    scan_kernel<<<dim3(1), dim3(1024), 0, stream>>>(bcounts, bstart, bcursor);
    scatter_kernel<<<dim3(NBLK), blk, 0, stream>>>(esrc, edst, bcursor, srt);

    // layer 1 (din=15, input x1)
    prep_kernel<<<gN, blk, 0, stream>>>(nullptr, x1, W[0][0], W[0][1], W[0][2], W[0][3], xl, xr, 15);
    gather_kernel<<<dim3(NB), blk, 0, stream>>>(srt, bstart, xl, xr, W[0][4], W[0][5], hA);

    // layer 2 (din=25, input [hA, x1])
    prep_kernel<<<gN, blk, 0, stream>>>(hA, x1, W[1][0], W[1][1], W[1][2], W[1][3], xl, xr, 25);
    gather_kernel<<<dim3(NB), blk, 0, stream>>>(srt, bstart, xl, xr, W[1][4], W[1][5], hA);

    // layer 3 (din=25, input [hA, x1])
    prep_kernel<<<gN, blk, 0, stream>>>(hA, x1, W[2][0], W[2][1], W[2][2], W[2][3], xl, xr, 25);
    gather_kernel<<<dim3(NB), blk, 0, stream>>>(srt, bstart, xl, xr, W[2][4], W[2][5], hA);

    // heads
    value_kernel<<<gN, blk, 0, stream>>>(hA, x1, x2, lin_W, lin_b, lin2_W, lin2_b, Vsum);
    orders_kernel<<<gT, blk, 0, stream>>>(hA, x1, move_type, m_src, m_dst, m_target,
                                          m_armies, move_id, aaa_W, aaa_b, ccc_W, ccc_b,
                                          attl_W, attl_b, pi_W, pi_b, al, piv, amax);
    orders2_kernel<<<gT, blk, 0, stream>>>(al, piv, move_id, amax, den_m, num_m);
    final_kernel<<<dim3(1), blk, 0, stream>>>(num_m, den_m, Vsum, (float*)d_out);
}

// Round 4
// 975.618 us; speedup vs baseline: 5.7129x; 1.0670x over previous
//
#include <hip/hip_runtime.h>
#include <cmath>

#define NN 100000
#define NE 3200000
#define TT 2048
#define MM 256
#define STR 16    // padded row stride (floats) for 10-wide node arrays -> 64B rows
#define BSZ 64    // nodes per bucket
#define NB 1563   // ceil(NN/BSZ)
#define EPB 8192  // edges per scatter/hist block
#define NBLK 391  // ceil(NE/EPB)

__device__ __forceinline__ void atomicMaxF(float* addr, float v) {
    if (v >= 0.f) atomicMax((int*)addr, __float_as_int(v));
    else          atomicMin((unsigned int*)addr, __float_as_uint(v));
}

// ---------------- init: zero bucket counts + small buffers ----------------
__global__ __launch_bounds__(1024) void init_kernel(int* bcounts, float* amax, float* den_m,
                                                    float* num_m, float* Vsum) {
    int i = blockIdx.x * 1024 + threadIdx.x;
    if (i < NB) bcounts[i] = 0;
    if (i < MM) { amax[i] = -INFINITY; den_m[i] = 0.f; num_m[i] = 0.f; }
    if (i == 0) Vsum[0] = 0.f;
}

// ---------------- bucket histogram (LDS pre-aggregated) ----------------
__global__ __launch_bounds__(256) void hist_kernel(const int* __restrict__ dst,
                                                   int* __restrict__ bcounts) {
    __shared__ int h[NB];
    int tid = threadIdx.x;
    for (int i = tid; i < NB; i += 256) h[i] = 0;
    __syncthreads();
    int base = blockIdx.x * EPB;
    int end = base + EPB; if (end > NE) end = NE;
    for (int i = base + tid; i < end; i += 256) atomicAdd(&h[dst[i] >> 6], 1);
    __syncthreads();
    for (int i = tid; i < NB; i += 256) { int n = h[i]; if (n) atomicAdd(&bcounts[i], n); }
}

// ---------------- exclusive scan over NB buckets (single block) ----------------
__global__ __launch_bounds__(1024) void scan_kernel(const int* __restrict__ bcounts,
                                                    int* __restrict__ bstart,
                                                    int* __restrict__ bcursor) {
    __shared__ int ssum[1024];
    int tid = threadIdx.x;
    const int per = (NB + 1023) / 1024;  // 2
    int base = tid * per;
    int s = 0;
    for (int i = 0; i < per; i++) {
        int idx = base + i;
        if (idx < NB) s += bcounts[idx];
    }
    ssum[tid] = s;
    __syncthreads();
    for (int off = 1; off < 1024; off <<= 1) {
        int v = (tid >= off) ? ssum[tid - off] : 0;
        __syncthreads();
        ssum[tid] += v;
        __syncthreads();
    }
    int run = ssum[tid] - s;
    for (int i = 0; i < per; i++) {
        int idx = base + i;
        if (idx < NB) {
            bstart[idx] = run;
            bcursor[idx] = run;
            run += bcounts[idx];
        }
    }
    if (tid == 0) bstart[NB] = NE;
}

// ---------------- scatter: block-aggregated reservations, packed (local_dst,src) -------
__global__ __launch_bounds__(256) void scatter_kernel(const int* __restrict__ src,
                                                      const int* __restrict__ dst,
                                                      int* __restrict__ bcursor,
                                                      int* __restrict__ srt) {
    __shared__ int h[NB];   // local count -> global base
    __shared__ int c[NB];   // local running cursor
    int tid = threadIdx.x;
    for (int i = tid; i < NB; i += 256) h[i] = 0;
    __syncthreads();
    int base = blockIdx.x * EPB;
    int end = base + EPB; if (end > NE) end = NE;
    for (int i = base + tid; i < end; i += 256) atomicAdd(&h[dst[i] >> 6], 1);
    __syncthreads();
    for (int i = tid; i < NB; i += 256) {
        int n = h[i];
        h[i] = n ? atomicAdd(&bcursor[i], n) : 0;
        c[i] = 0;
    }
    __syncthreads();
    for (int i = base + tid; i < end; i += 256) {
        int d = dst[i];
        int b = d >> 6;
        int off = atomicAdd(&c[b], 1);
        srt[h[b] + off] = ((d & 63) << 17) | src[i];
    }
}

// ---------------- per-layer: compute xl, xr ----------------
__global__ __launch_bounds__(256) void prep_kernel(
    const float* __restrict__ hprev,   // [NN,STR] (first 10 cols valid) or nullptr
    const float* __restrict__ x1,      // [NN,15]
    const float* __restrict__ Wl, const float* __restrict__ bl,
    const float* __restrict__ Wr, const float* __restrict__ br,
    float* __restrict__ xl, float* __restrict__ xr,
    int din)                           // 15 or 25
{
    __shared__ float sWl[250], sWr[250], sbl[10], sbr[10];
    int tid = threadIdx.x;
    int nw = 10 * din;
    for (int i = tid; i < nw; i += blockDim.x) { sWl[i] = Wl[i]; sWr[i] = Wr[i]; }
    if (tid < 10) { sbl[tid] = bl[tid]; sbr[tid] = br[tid]; }
    __syncthreads();
    int n = blockIdx.x * blockDim.x + tid;
    if (n >= NN) return;

    float in[25];
    if (din == 15) {
        #pragma unroll
        for (int k = 0; k < 15; k++) in[k] = x1[n * 15 + k];
    } else {
        #pragma unroll
        for (int k = 0; k < 10; k++) in[k] = hprev[n * STR + k];
        #pragma unroll
        for (int k = 0; k < 15; k++) in[10 + k] = x1[n * 15 + k];
    }

    #pragma unroll
    for (int j = 0; j < 10; j++) {
        float sl = sbl[j], sr = sbr[j];
        for (int k = 0; k < din; k++) {
            sl += in[k] * sWl[j * din + k];
            sr += in[k] * sWr[j * din + k];
        }
        xl[n * STR + j] = sl;
        xr[n * STR + j] = sr;
    }
}

// ---------------- per-layer: bucket gather, edge-parallel, 4x MLP, LDS accumulators ----
// One block per bucket of 64 dst nodes. Odd strides (11) -> bank spread.
__global__ __launch_bounds__(256, 5) void gather_kernel(
    const int* __restrict__ srt, const int* __restrict__ bstart,
    const float* __restrict__ xl, const float* __restrict__ xr,
    const float* __restrict__ att, const float* __restrict__ bias,
    float* __restrict__ hout)
{
    __shared__ float accs[BSZ * 11];  // [local_dst][0..9]=acc, [10]=den
    __shared__ float xrs[BSZ * 11];   // [local_dst][0..9]=xr row (stride 11: odd)
    __shared__ float sat[10];
    int b = blockIdx.x, tid = threadIdx.x;
    if (tid < 10) sat[tid] = att[tid];
    __syncthreads();

    int n0 = b * BSZ;
    if (tid < BSZ) {
        int n = n0 + tid;
        if (n < NN) {
            const float* xln = xl + n * STR;
            const float* xrn = xr + n * STR;
            float a[10], r[10];
            #pragma unroll
            for (int k = 0; k < 10; k++) { a[k] = xln[k]; r[k] = xrn[k]; }
            #pragma unroll
            for (int k = 0; k < 10; k++) xrs[tid * 11 + k] = r[k];
            float e = 0.f;
            #pragma unroll
            for (int k = 0; k < 10; k++) {
                float t = a[k] + r[k];
                t = t > 0.f ? t : 0.2f * t;
                e += sat[k] * t;
            }
            float ex = __expf(e);
            #pragma unroll
            for (int k = 0; k < 10; k++) accs[tid * 11 + k] = ex * a[k];
            accs[tid * 11 + 10] = ex;
        } else {
            #pragma unroll
            for (int k = 0; k < 11; k++) { accs[tid * 11 + k] = 0.f; xrs[tid * 11 + k] = 0.f; }
        }
    }
    __syncthreads();

    int i0 = bstart[b], i1 = bstart[b + 1];
    for (int base = i0; base < i1; base += 1024) {
        int p[4];
        #pragma unroll
        for (int j = 0; j < 4; j++) {
            int i = base + j * 256 + tid;
            p[j] = (i < i1) ? srt[i] : -1;
        }
        // issue all 12 row-load instructions before consuming (4x MLP)
        float4 v0[4], v1[4]; float2 v2[4];
        #pragma unroll
        for (int j = 0; j < 4; j++) {
            int s = (p[j] < 0) ? 0 : (p[j] & 0x1FFFF);
            const float* xls = xl + s * STR;
            v0[j] = *(const float4*)(xls);
            v1[j] = *(const float4*)(xls + 4);
            v2[j] = *(const float2*)(xls + 8);
        }
        #pragma unroll
        for (int j = 0; j < 4; j++) {
            if (p[j] < 0) continue;
            int ld = p[j] >> 17;
            float a[10] = {v0[j].x, v0[j].y, v0[j].z, v0[j].w,
                           v1[j].x, v1[j].y, v1[j].z, v1[j].w, v2[j].x, v2[j].y};
            const float* r = xrs + ld * 11;
            float e = 0.f;
            #pragma unroll
            for (int k = 0; k < 10; k++) {
                float t = a[k] + r[k];
                t = t > 0.f ? t : 0.2f * t;
                e += sat[k] * t;
            }
            float ex = __expf(e);
            float* ac = accs + ld * 11;
            #pragma unroll
            for (int k = 0; k < 10; k++) atomicAdd(ac + k, ex * a[k]);
            atomicAdd(ac + 10, ex);
        }
    }
    __syncthreads();

    if (tid < BSZ) {
        int n = n0 + tid;
        if (n < NN) {
            float inv = 1.f / accs[tid * 11 + 10];
            #pragma unroll
            for (int k = 0; k < 10; k++) {
                float v = accs[tid * 11 + k] * inv + bias[k];
                hout[n * STR + k] = v > 0.f ? v : 0.f;
            }
        }
    }
}

// ---------------- value head ----------------
__global__ __launch_bounds__(256) void value_kernel(
    const float* __restrict__ x, const float* __restrict__ x1, const float* __restrict__ x2,
    const float* __restrict__ lin_W, const float* __restrict__ lin_b,
    const float* __restrict__ lin2_W, const float* __restrict__ lin2_b,
    float* __restrict__ Vsum)
{
    __shared__ float sW[15 * 29], sb[15], sW2[15];
    __shared__ float red[256];
    int tid = threadIdx.x;
    for (int i = tid; i < 15 * 29; i += 256) sW[i] = lin_W[i];
    if (tid < 15) { sb[tid] = lin_b[tid]; sW2[tid] = lin2_W[tid]; }
    __syncthreads();
    int n = blockIdx.x * 256 + tid;
    float local = 0.f;
    if (n < NN) {
        float in[29];
        #pragma unroll
        for (int k = 0; k < 10; k++) in[k] = x[n * STR + k];
        #pragma unroll
        for (int k = 0; k < 15; k++) in[10 + k] = x1[n * 15 + k];
        #pragma unroll
        for (int k = 0; k < 4; k++) in[25 + k] = x2[k];
        float sc = lin2_b[0];
        #pragma unroll
        for (int j = 0; j < 15; j++) {
            float s = sb[j];
            for (int k = 0; k < 29; k++) s += in[k] * sW[j * 29 + k];
            sc += (s > 0.f ? s : 0.f) * sW2[j];
        }
        local = sc;
    }
    red[tid] = local;
    __syncthreads();
    for (int off = 128; off > 0; off >>= 1) {
        if (tid < off) red[tid] += red[tid + off];
        __syncthreads();
    }
    if (tid == 0) atomicAdd(Vsum, red[0]);
}

// ---------------- order head, stage 1 ----------------
__global__ __launch_bounds__(256) void orders_kernel(
    const float* __restrict__ x, const float* __restrict__ x1,
    const int* __restrict__ move_type, const int* __restrict__ m_src,
    const int* __restrict__ m_dst, const int* __restrict__ m_target,
    const float* __restrict__ m_armies, const int* __restrict__ move_id,
    const float* __restrict__ aaa_W, const float* __restrict__ aaa_b,
    const float* __restrict__ ccc_W, const float* __restrict__ ccc_b,
    const float* __restrict__ attl_W, const float* __restrict__ attl_b,
    const float* __restrict__ pi_W, const float* __restrict__ pi_b,
    float* __restrict__ al_out, float* __restrict__ pi_out, float* __restrict__ amax)
{
    __shared__ float sA[20 * 48], sC[20 * 23], sAb[20], sCb[20];
    int tid = threadIdx.x;
    for (int i = tid; i < 20 * 48; i += 256) sA[i] = aaa_W[i];
    for (int i = tid; i < 20 * 23; i += 256) sC[i] = ccc_W[i];
    if (tid < 20) { sAb[tid] = aaa_b[tid]; sCb[tid] = ccc_b[tid]; }
    __syncthreads();
    int t = blockIdx.x * 256 + tid;
    if (t >= TT) return;

    float armies = m_armies[t];
    float hm[20];
    if (move_type[t] == 0) {
        int sn = m_src[t], dn = m_dst[t];
        float f[48];
        #pragma unroll
        for (int k = 0; k < 10; k++) f[k] = x[sn * STR + k];
        #pragma unroll
        for (int k = 0; k < 10; k++) f[10 + k] = x[dn * STR + k];
        #pragma unroll
        for (int k = 0; k < 12; k++) f[20 + k] = x1[sn * 15 + 3 + k];
        #pragma unroll
        for (int k = 0; k < 14; k++) f[32 + k] = x1[dn * 15 + 1 + k];
        f[46] = armies;
        f[47] = 0.6f * armies - 0.7f * (x1[dn * 15 + 3] + x1[dn * 15 + 4]);
        #pragma unroll
        for (int j = 0; j < 20; j++) {
            float s = sAb[j];
            for (int k = 0; k < 48; k++) s += f[k] * sA[j * 48 + k];
            hm[j] = s > 0.f ? s : 0.f;
        }
    } else {
        int tg = m_target[t];
        float f[23];
        #pragma unroll
        for (int k = 0; k < 10; k++) f[k] = x[tg * STR + k];
        #pragma unroll
        for (int k = 0; k < 12; k++) f[10 + k] = x1[tg * 15 + 3 + k];
        f[22] = armies;
        #pragma unroll
        for (int j = 0; j < 20; j++) {
            float s = sCb[j];
            for (int k = 0; k < 23; k++) s += f[k] * sC[j * 23 + k];
            hm[j] = s > 0.f ? s : 0.f;
        }
    }
    float a = attl_b[0], p = pi_b[0];
    #pragma unroll
    for (int j = 0; j < 20; j++) { a += hm[j] * attl_W[j]; p += hm[j] * pi_W[j]; }
    al_out[t] = a;
    pi_out[t] = p;
    atomicMaxF(&amax[move_id[t]], a);
}

// ---------------- order head, stage 2 ----------------
__global__ __launch_bounds__(256) void orders2_kernel(
    const float* __restrict__ al, const float* __restrict__ piv,
    const int* __restrict__ move_id, const float* __restrict__ amax,
    float* __restrict__ den_m, float* __restrict__ num_m)
{
    int t = blockIdx.x * 256 + threadIdx.x;
    if (t >= TT) return;
    int m = move_id[t];
    float ex = __expf(al[t] - amax[m]);
    atomicAdd(den_m + m, ex);
    atomicAdd(num_m + m, ex * piv[t]);
}

// ---------------- final: p -> log_softmax, V -> tanh(mean) ----------------
__global__ __launch_bounds__(256) void final_kernel(
    const float* __restrict__ num_m, const float* __restrict__ den_m,
    const float* __restrict__ Vsum, float* __restrict__ out)
{
    __shared__ float sh[256];
    __shared__ float s_max, s_sum;
    int m = threadIdx.x;
    float p = num_m[m] / den_m[m];
    sh[m] = p;
    __syncthreads();
    for (int off = 128; off > 0; off >>= 1) {
        if (m < off) sh[m] = fmaxf(sh[m], sh[m + off]);
        __syncthreads();
    }
    if (m == 0) s_max = sh[0];
    __syncthreads();
    float e = __expf(p - s_max);
    sh[m] = e;
    __syncthreads();
    for (int off = 128; off > 0; off >>= 1) {
        if (m < off) sh[m] += sh[m + off];
        __syncthreads();
    }
    if (m == 0) s_sum = sh[0];
    __syncthreads();
    out[1 + m] = p - s_max - logf(s_sum);
    if (m == 0) out[0] = tanhf(Vsum[0] / (float)NN);
}

extern "C" void kernel_launch(void* const* d_in, const int* in_sizes, int n_in,
                              void* d_out, int out_size, void* d_ws, size_t ws_size,
                              hipStream_t stream) {
    const float* x1        = (const float*)d_in[0];
    const float* x2        = (const float*)d_in[1];
    const int*   esrc      = (const int*)d_in[2];
    const int*   edst      = (const int*)d_in[3];
    const int*   move_type = (const int*)d_in[4];
    const int*   m_src     = (const int*)d_in[5];
    const int*   m_dst     = (const int*)d_in[6];
    const int*   m_target  = (const int*)d_in[7];
    const float* m_armies  = (const float*)d_in[8];
    const int*   move_id   = (const int*)d_in[9];
    const float* W[3][6];
    for (int l = 0; l < 3; l++)
        for (int j = 0; j < 6; j++)
            W[l][j] = (const float*)d_in[10 + l * 6 + j];
    const float* lin_W  = (const float*)d_in[28];
    const float* lin_b  = (const float*)d_in[29];
    const float* lin2_W = (const float*)d_in[30];
    const float* lin2_b = (const float*)d_in[31];
    const float* aaa_W  = (const float*)d_in[32];
    const float* aaa_b  = (const float*)d_in[33];
    const float* ccc_W  = (const float*)d_in[34];
    const float* ccc_b  = (const float*)d_in[35];
    const float* attl_W = (const float*)d_in[36];
    const float* attl_b = (const float*)d_in[37];
    const float* pi_W   = (const float*)d_in[38];
    const float* pi_b   = (const float*)d_in[39];

    // workspace layout (~33 MB)
    float* ws = (float*)d_ws;
    float* xl    = ws; ws += NN * STR;
    float* xr    = ws; ws += NN * STR;
    float* hA    = ws; ws += NN * STR;
    float* al    = ws; ws += TT;
    float* piv   = ws; ws += TT;
    float* amax  = ws; ws += MM;
    float* den_m = ws; ws += MM;
    float* num_m = ws; ws += MM;
    float* Vsum  = ws; ws += 1;
    int* iws = (int*)ws;
    int* bcounts = iws; iws += NB;
    int* bstart  = iws; iws += NB + 1;
    int* bcursor = iws; iws += NB;
    int* srt     = iws; iws += NE;

    dim3 blk(256);
    dim3 gN((NN + 255) / 256);
    dim3 gT(TT / 256);

    // build bucketed CSR once; reused by all 3 layers
    init_kernel<<<dim3(2), dim3(1024), 0, stream>>>(bcounts, amax, den_m, num_m, Vsum);
    hist_kernel<<<dim3(NBLK), blk, 0, stream>>>(edst, bcounts);
    scan_kernel<<<dim3(1), dim3(1024), 0, stream>>>(bcounts, bstart, bcursor);
    scatter_kernel<<<dim3(NBLK), blk, 0, stream>>>(esrc, edst, bcursor, srt);

    // layer 1 (din=15, input x1)
    prep_kernel<<<gN, blk, 0, stream>>>(nullptr, x1, W[0][0], W[0][1], W[0][2], W[0][3], xl, xr, 15);
    gather_kernel<<<dim3(NB), blk, 0, stream>>>(srt, bstart, xl, xr, W[0][4], W[0][5], hA);

    // layer 2 (din=25, input [hA, x1])
    prep_kernel<<<gN, blk, 0, stream>>>(hA, x1, W[1][0], W[1][1], W[1][2], W[1][3], xl, xr, 25);
    gather_kernel<<<dim3(NB), blk, 0, stream>>>(srt, bstart, xl, xr, W[1][4], W[1][5], hA);

    // layer 3 (din=25, input [hA, x1])
    prep_kernel<<<gN, blk, 0, stream>>>(hA, x1, W[2][0], W[2][1], W[2][2], W[2][3], xl, xr, 25);
    gather_kernel<<<dim3(NB), blk, 0, stream>>>(srt, bstart, xl, xr, W[2][4], W[2][5], hA);

    // heads
    value_kernel<<<gN, blk, 0, stream>>>(hA, x1, x2, lin_W, lin_b, lin2_W, lin2_b, Vsum);
    orders_kernel<<<gT, blk, 0, stream>>>(hA, x1, move_type, m_src, m_dst, m_target,
                                          m_armies, move_id, aaa_W, aaa_b, ccc_W, ccc_b,
                                          attl_W, attl_b, pi_W, pi_b, al, piv, amax);
    orders2_kernel<<<gT, blk, 0, stream>>>(al, piv, move_id, amax, den_m, num_m);
    final_kernel<<<dim3(1), blk, 0, stream>>>(num_m, den_m, Vsum, (float*)d_out);
}

// Round 5
// 968.712 us; speedup vs baseline: 5.7536x; 1.0071x over previous
//
#include <hip/hip_runtime.h>
#include <cmath>

#define NN 100000
#define NE 3200000
#define TT 2048
#define MM 256
#define STR 16    // padded row stride (floats) for 10-wide node arrays -> 64B rows
#define HSTR 16   // row stride (ushorts) for bf16 xl copy -> 32B rows, 3.2MB total (L2-resident)
#define BSZ 64    // nodes per bucket
#define NB 1563   // ceil(NN/BSZ)
#define EPB 8192  // edges per scatter/hist block
#define NBLK 391  // ceil(NE/EPB)

__device__ __forceinline__ void atomicMaxF(float* addr, float v) {
    if (v >= 0.f) atomicMax((int*)addr, __float_as_int(v));
    else          atomicMin((unsigned int*)addr, __float_as_uint(v));
}

__device__ __forceinline__ unsigned short f2bf(float x) {
    unsigned u = __float_as_uint(x);
    u += 0x7FFFu + ((u >> 16) & 1u);   // round-to-nearest-even
    return (unsigned short)(u >> 16);
}

// ---------------- init: zero bucket counts + small buffers ----------------
__global__ __launch_bounds__(1024) void init_kernel(int* bcounts, float* amax, float* den_m,
                                                    float* num_m, float* Vsum) {
    int i = blockIdx.x * 1024 + threadIdx.x;
    if (i < NB) bcounts[i] = 0;
    if (i < MM) { amax[i] = -INFINITY; den_m[i] = 0.f; num_m[i] = 0.f; }
    if (i == 0) Vsum[0] = 0.f;
}

// ---------------- bucket histogram (LDS pre-aggregated) ----------------
__global__ __launch_bounds__(256) void hist_kernel(const int* __restrict__ dst,
                                                   int* __restrict__ bcounts) {
    __shared__ int h[NB];
    int tid = threadIdx.x;
    for (int i = tid; i < NB; i += 256) h[i] = 0;
    __syncthreads();
    int base = blockIdx.x * EPB;
    int end = base + EPB; if (end > NE) end = NE;
    for (int i = base + tid; i < end; i += 256) atomicAdd(&h[dst[i] >> 6], 1);
    __syncthreads();
    for (int i = tid; i < NB; i += 256) { int n = h[i]; if (n) atomicAdd(&bcounts[i], n); }
}

// ---------------- exclusive scan over NB buckets (single block) ----------------
__global__ __launch_bounds__(1024) void scan_kernel(const int* __restrict__ bcounts,
                                                    int* __restrict__ bstart,
                                                    int* __restrict__ bcursor) {
    __shared__ int ssum[1024];
    int tid = threadIdx.x;
    const int per = (NB + 1023) / 1024;  // 2
    int base = tid * per;
    int s = 0;
    for (int i = 0; i < per; i++) {
        int idx = base + i;
        if (idx < NB) s += bcounts[idx];
    }
    ssum[tid] = s;
    __syncthreads();
    for (int off = 1; off < 1024; off <<= 1) {
        int v = (tid >= off) ? ssum[tid - off] : 0;
        __syncthreads();
        ssum[tid] += v;
        __syncthreads();
    }
    int run = ssum[tid] - s;
    for (int i = 0; i < per; i++) {
        int idx = base + i;
        if (idx < NB) {
            bstart[idx] = run;
            bcursor[idx] = run;
            run += bcounts[idx];
        }
    }
    if (tid == 0) bstart[NB] = NE;
}

// ---------------- scatter: block-aggregated reservations, packed (local_dst,src) -------
__global__ __launch_bounds__(256) void scatter_kernel(const int* __restrict__ src,
                                                      const int* __restrict__ dst,
                                                      int* __restrict__ bcursor,
                                                      int* __restrict__ srt) {
    __shared__ int h[NB];   // local count -> global base
    __shared__ int c[NB];   // local running cursor
    int tid = threadIdx.x;
    for (int i = tid; i < NB; i += 256) h[i] = 0;
    __syncthreads();
    int base = blockIdx.x * EPB;
    int end = base + EPB; if (end > NE) end = NE;
    for (int i = base + tid; i < end; i += 256) atomicAdd(&h[dst[i] >> 6], 1);
    __syncthreads();
    for (int i = tid; i < NB; i += 256) {
        int n = h[i];
        h[i] = n ? atomicAdd(&bcursor[i], n) : 0;
        c[i] = 0;
    }
    __syncthreads();
    for (int i = base + tid; i < end; i += 256) {
        int d = dst[i];
        int b = d >> 6;
        int off = atomicAdd(&c[b], 1);
        srt[h[b] + off] = ((d & 63) << 17) | src[i];
    }
}

// ---------------- per-layer: compute xl (fp32 + bf16 copy), xr ----------------
__global__ __launch_bounds__(256) void prep_kernel(
    const float* __restrict__ hprev,   // [NN,STR] (first 10 cols valid) or nullptr
    const float* __restrict__ x1,      // [NN,15]
    const float* __restrict__ Wl, const float* __restrict__ bl,
    const float* __restrict__ Wr, const float* __restrict__ br,
    float* __restrict__ xl, float* __restrict__ xr,
    unsigned short* __restrict__ xlh,  // [NN,HSTR] bf16 rows (32B stride -> L2-resident)
    int din)                           // 15 or 25
{
    __shared__ float sWl[250], sWr[250], sbl[10], sbr[10];
    int tid = threadIdx.x;
    int nw = 10 * din;
    for (int i = tid; i < nw; i += blockDim.x) { sWl[i] = Wl[i]; sWr[i] = Wr[i]; }
    if (tid < 10) { sbl[tid] = bl[tid]; sbr[tid] = br[tid]; }
    __syncthreads();
    int n = blockIdx.x * blockDim.x + tid;
    if (n >= NN) return;

    float in[25];
    if (din == 15) {
        #pragma unroll
        for (int k = 0; k < 15; k++) in[k] = x1[n * 15 + k];
    } else {
        #pragma unroll
        for (int k = 0; k < 10; k++) in[k] = hprev[n * STR + k];
        #pragma unroll
        for (int k = 0; k < 15; k++) in[10 + k] = x1[n * 15 + k];
    }

    float slv[10];
    #pragma unroll
    for (int j = 0; j < 10; j++) {
        float sl = sbl[j], sr = sbr[j];
        for (int k = 0; k < din; k++) {
            sl += in[k] * sWl[j * din + k];
            sr += in[k] * sWr[j * din + k];
        }
        slv[j] = sl;
        xl[n * STR + j] = sl;
        xr[n * STR + j] = sr;
    }
    // bf16 copy of xl, packed 2 per uint
    unsigned* hp = (unsigned*)(xlh + n * HSTR);
    #pragma unroll
    for (int j = 0; j < 5; j++) {
        unsigned lo = f2bf(slv[2 * j]);
        unsigned hi = f2bf(slv[2 * j + 1]);
        hp[j] = lo | (hi << 16);
    }
}

// ---------------- per-layer: bucket gather, edge-parallel, 4x MLP, bf16 xl gathers ----
// One block per bucket of 64 dst nodes. Odd LDS strides (11) -> bank spread.
__global__ __launch_bounds__(256, 5) void gather_kernel(
    const int* __restrict__ srt, const int* __restrict__ bstart,
    const float* __restrict__ xl, const float* __restrict__ xr,
    const unsigned short* __restrict__ xlh,
    const float* __restrict__ att, const float* __restrict__ bias,
    float* __restrict__ hout)
{
    __shared__ float accs[BSZ * 11];  // [local_dst][0..9]=acc, [10]=den
    __shared__ float xrs[BSZ * 11];   // [local_dst][0..9]=xr row
    __shared__ float sat[10];
    int b = blockIdx.x, tid = threadIdx.x;
    if (tid < 10) sat[tid] = att[tid];
    __syncthreads();

    int n0 = b * BSZ;
    if (tid < BSZ) {
        int n = n0 + tid;
        if (n < NN) {
            const float* xln = xl + n * STR;
            const float* xrn = xr + n * STR;
            float a[10], r[10];
            #pragma unroll
            for (int k = 0; k < 10; k++) { a[k] = xln[k]; r[k] = xrn[k]; }
            #pragma unroll
            for (int k = 0; k < 10; k++) xrs[tid * 11 + k] = r[k];
            float e = 0.f;
            #pragma unroll
            for (int k = 0; k < 10; k++) {
                float t = a[k] + r[k];
                t = t > 0.f ? t : 0.2f * t;
                e += sat[k] * t;
            }
            float ex = __expf(e);
            #pragma unroll
            for (int k = 0; k < 10; k++) accs[tid * 11 + k] = ex * a[k];
            accs[tid * 11 + 10] = ex;
        } else {
            #pragma unroll
            for (int k = 0; k < 11; k++) { accs[tid * 11 + k] = 0.f; xrs[tid * 11 + k] = 0.f; }
        }
    }
    __syncthreads();

    int i0 = bstart[b], i1 = bstart[b + 1];
    for (int base = i0; base < i1; base += 1024) {
        int p[4];
        #pragma unroll
        for (int j = 0; j < 4; j++) {
            int i = base + j * 256 + tid;
            p[j] = (i < i1) ? srt[i] : -1;
        }
        // issue all 8 row-load instructions before consuming (4x MLP)
        uint4 q[4]; unsigned q2[4];
        #pragma unroll
        for (int j = 0; j < 4; j++) {
            int s = (p[j] < 0) ? 0 : (p[j] & 0x1FFFF);
            const unsigned short* row = xlh + s * HSTR;
            q[j] = *(const uint4*)(row);
            q2[j] = *(const unsigned*)(row + 8);
        }
        #pragma unroll
        for (int j = 0; j < 4; j++) {
            if (p[j] < 0) continue;
            int ld = p[j] >> 17;
            float a[10];
            a[0] = __uint_as_float(q[j].x << 16);
            a[1] = __uint_as_float(q[j].x & 0xFFFF0000u);
            a[2] = __uint_as_float(q[j].y << 16);
            a[3] = __uint_as_float(q[j].y & 0xFFFF0000u);
            a[4] = __uint_as_float(q[j].z << 16);
            a[5] = __uint_as_float(q[j].z & 0xFFFF0000u);
            a[6] = __uint_as_float(q[j].w << 16);
            a[7] = __uint_as_float(q[j].w & 0xFFFF0000u);
            a[8] = __uint_as_float(q2[j] << 16);
            a[9] = __uint_as_float(q2[j] & 0xFFFF0000u);
            const float* r = xrs + ld * 11;
            float e = 0.f;
            #pragma unroll
            for (int k = 0; k < 10; k++) {
                float t = a[k] + r[k];
                t = t > 0.f ? t : 0.2f * t;
                e += sat[k] * t;
            }
            float ex = __expf(e);
            float* ac = accs + ld * 11;
            #pragma unroll
            for (int k = 0; k < 10; k++) atomicAdd(ac + k, ex * a[k]);
            atomicAdd(ac + 10, ex);
        }
    }
    __syncthreads();

    if (tid < BSZ) {
        int n = n0 + tid;
        if (n < NN) {
            float inv = 1.f / accs[tid * 11 + 10];
            #pragma unroll
            for (int k = 0; k < 10; k++) {
                float v = accs[tid * 11 + k] * inv + bias[k];
                hout[n * STR + k] = v > 0.f ? v : 0.f;
            }
        }
    }
}

// ---------------- value head ----------------
__global__ __launch_bounds__(256) void value_kernel(
    const float* __restrict__ x, const float* __restrict__ x1, const float* __restrict__ x2,
    const float* __restrict__ lin_W, const float* __restrict__ lin_b,
    const float* __restrict__ lin2_W, const float* __restrict__ lin2_b,
    float* __restrict__ Vsum)
{
    __shared__ float sW[15 * 29], sb[15], sW2[15];
    __shared__ float red[256];
    int tid = threadIdx.x;
    for (int i = tid; i < 15 * 29; i += 256) sW[i] = lin_W[i];
    if (tid < 15) { sb[tid] = lin_b[tid]; sW2[tid] = lin2_W[tid]; }
    __syncthreads();
    int n = blockIdx.x * 256 + tid;
    float local = 0.f;
    if (n < NN) {
        float in[29];
        #pragma unroll
        for (int k = 0; k < 10; k++) in[k] = x[n * STR + k];
        #pragma unroll
        for (int k = 0; k < 15; k++) in[10 + k] = x1[n * 15 + k];
        #pragma unroll
        for (int k = 0; k < 4; k++) in[25 + k] = x2[k];
        float sc = lin2_b[0];
        #pragma unroll
        for (int j = 0; j < 15; j++) {
            float s = sb[j];
            for (int k = 0; k < 29; k++) s += in[k] * sW[j * 29 + k];
            sc += (s > 0.f ? s : 0.f) * sW2[j];
        }
        local = sc;
    }
    red[tid] = local;
    __syncthreads();
    for (int off = 128; off > 0; off >>= 1) {
        if (tid < off) red[tid] += red[tid + off];
        __syncthreads();
    }
    if (tid == 0) atomicAdd(Vsum, red[0]);
}

// ---------------- order head, stage 1 ----------------
__global__ __launch_bounds__(256) void orders_kernel(
    const float* __restrict__ x, const float* __restrict__ x1,
    const int* __restrict__ move_type, const int* __restrict__ m_src,
    const int* __restrict__ m_dst, const int* __restrict__ m_target,
    const float* __restrict__ m_armies, const int* __restrict__ move_id,
    const float* __restrict__ aaa_W, const float* __restrict__ aaa_b,
    const float* __restrict__ ccc_W, const float* __restrict__ ccc_b,
    const float* __restrict__ attl_W, const float* __restrict__ attl_b,
    const float* __restrict__ pi_W, const float* __restrict__ pi_b,
    float* __restrict__ al_out, float* __restrict__ pi_out, float* __restrict__ amax)
{
    __shared__ float sA[20 * 48], sC[20 * 23], sAb[20], sCb[20];
    int tid = threadIdx.x;
    for (int i = tid; i < 20 * 48; i += 256) sA[i] = aaa_W[i];
    for (int i = tid; i < 20 * 23; i += 256) sC[i] = ccc_W[i];
    if (tid < 20) { sAb[tid] = aaa_b[tid]; sCb[tid] = ccc_b[tid]; }
    __syncthreads();
    int t = blockIdx.x * 256 + tid;
    if (t >= TT) return;

    float armies = m_armies[t];
    float hm[20];
    if (move_type[t] == 0) {
        int sn = m_src[t], dn = m_dst[t];
        float f[48];
        #pragma unroll
        for (int k = 0; k < 10; k++) f[k] = x[sn * STR + k];
        #pragma unroll
        for (int k = 0; k < 10; k++) f[10 + k] = x[dn * STR + k];
        #pragma unroll
        for (int k = 0; k < 12; k++) f[20 + k] = x1[sn * 15 + 3 + k];
        #pragma unroll
        for (int k = 0; k < 14; k++) f[32 + k] = x1[dn * 15 + 1 + k];
        f[46] = armies;
        f[47] = 0.6f * armies - 0.7f * (x1[dn * 15 + 3] + x1[dn * 15 + 4]);
        #pragma unroll
        for (int j = 0; j < 20; j++) {
            float s = sAb[j];
            for (int k = 0; k < 48; k++) s += f[k] * sA[j * 48 + k];
            hm[j] = s > 0.f ? s : 0.f;
        }
    } else {
        int tg = m_target[t];
        float f[23];
        #pragma unroll
        for (int k = 0; k < 10; k++) f[k] = x[tg * STR + k];
        #pragma unroll
        for (int k = 0; k < 12; k++) f[10 + k] = x1[tg * 15 + 3 + k];
        f[22] = armies;
        #pragma unroll
        for (int j = 0; j < 20; j++) {
            float s = sCb[j];
            for (int k = 0; k < 23; k++) s += f[k] * sC[j * 23 + k];
            hm[j] = s > 0.f ? s : 0.f;
        }
    }
    float a = attl_b[0], p = pi_b[0];
    #pragma unroll
    for (int j = 0; j < 20; j++) { a += hm[j] * attl_W[j]; p += hm[j] * pi_W[j]; }
    al_out[t] = a;
    pi_out[t] = p;
    atomicMaxF(&amax[move_id[t]], a);
}

// ---------------- order head, stage 2 ----------------
__global__ __launch_bounds__(256) void orders2_kernel(
    const float* __restrict__ al, const float* __restrict__ piv,
    const int* __restrict__ move_id, const float* __restrict__ amax,
    float* __restrict__ den_m, float* __restrict__ num_m)
{
    int t = blockIdx.x * 256 + threadIdx.x;
    if (t >= TT) return;
    int m = move_id[t];
    float ex = __expf(al[t] - amax[m]);
    atomicAdd(den_m + m, ex);
    atomicAdd(num_m + m, ex * piv[t]);
}

// ---------------- final: p -> log_softmax, V -> tanh(mean) ----------------
__global__ __launch_bounds__(256) void final_kernel(
    const float* __restrict__ num_m, const float* __restrict__ den_m,
    const float* __restrict__ Vsum, float* __restrict__ out)
{
    __shared__ float sh[256];
    __shared__ float s_max, s_sum;
    int m = threadIdx.x;
    float p = num_m[m] / den_m[m];
    sh[m] = p;
    __syncthreads();
    for (int off = 128; off > 0; off >>= 1) {
        if (m < off) sh[m] = fmaxf(sh[m], sh[m + off]);
        __syncthreads();
    }
    if (m == 0) s_max = sh[0];
    __syncthreads();
    float e = __expf(p - s_max);
    sh[m] = e;
    __syncthreads();
    for (int off = 128; off > 0; off >>= 1) {
        if (m < off) sh[m] += sh[m + off];
        __syncthreads();
    }
    if (m == 0) s_sum = sh[0];
    __syncthreads();
    out[1 + m] = p - s_max - logf(s_sum);
    if (m == 0) out[0] = tanhf(Vsum[0] / (float)NN);
}

extern "C" void kernel_launch(void* const* d_in, const int* in_sizes, int n_in,
                              void* d_out, int out_size, void* d_ws, size_t ws_size,
                              hipStream_t stream) {
    const float* x1        = (const float*)d_in[0];
    const float* x2        = (const float*)d_in[1];
    const int*   esrc      = (const int*)d_in[2];
    const int*   edst      = (const int*)d_in[3];
    const int*   move_type = (const int*)d_in[4];
    const int*   m_src     = (const int*)d_in[5];
    const int*   m_dst     = (const int*)d_in[6];
    const int*   m_target  = (const int*)d_in[7];
    const float* m_armies  = (const float*)d_in[8];
    const int*   move_id   = (const int*)d_in[9];
    const float* W[3][6];
    for (int l = 0; l < 3; l++)
        for (int j = 0; j < 6; j++)
            W[l][j] = (const float*)d_in[10 + l * 6 + j];
    const float* lin_W  = (const float*)d_in[28];
    const float* lin_b  = (const float*)d_in[29];
    const float* lin2_W = (const float*)d_in[30];
    const float* lin2_b = (const float*)d_in[31];
    const float* aaa_W  = (const float*)d_in[32];
    const float* aaa_b  = (const float*)d_in[33];
    const float* ccc_W  = (const float*)d_in[34];
    const float* ccc_b  = (const float*)d_in[35];
    const float* attl_W = (const float*)d_in[36];
    const float* attl_b = (const float*)d_in[37];
    const float* pi_W   = (const float*)d_in[38];
    const float* pi_b   = (const float*)d_in[39];

    // workspace layout (~36 MB)
    float* ws = (float*)d_ws;
    float* xl    = ws; ws += NN * STR;
    float* xr    = ws; ws += NN * STR;
    float* hA    = ws; ws += NN * STR;
    float* al    = ws; ws += TT;
    float* piv   = ws; ws += TT;
    float* amax  = ws; ws += MM;
    float* den_m = ws; ws += MM;
    float* num_m = ws; ws += MM;
    float* Vsum  = ws; ws += 1;
    unsigned short* xlh = (unsigned short*)ws; ws += NN * HSTR / 2;
    int* iws = (int*)ws;
    int* bcounts = iws; iws += NB;
    int* bstart  = iws; iws += NB + 1;
    int* bcursor = iws; iws += NB;
    int* srt     = iws; iws += NE;

    dim3 blk(256);
    dim3 gN((NN + 255) / 256);
    dim3 gT(TT / 256);

    // build bucketed CSR once; reused by all 3 layers
    init_kernel<<<dim3(2), dim3(1024), 0, stream>>>(bcounts, amax, den_m, num_m, Vsum);
    hist_kernel<<<dim3(NBLK), blk, 0, stream>>>(edst, bcounts);
    scan_kernel<<<dim3(1), dim3(1024), 0, stream>>>(bcounts, bstart, bcursor);
    scatter_kernel<<<dim3(NBLK), blk, 0, stream>>>(esrc, edst, bcursor, srt);

    // layer 1 (din=15, input x1)
    prep_kernel<<<gN, blk, 0, stream>>>(nullptr, x1, W[0][0], W[0][1], W[0][2], W[0][3], xl, xr, xlh, 15);
    gather_kernel<<<dim3(NB), blk, 0, stream>>>(srt, bstart, xl, xr, xlh, W[0][4], W[0][5], hA);

    // layer 2 (din=25, input [hA, x1])
    prep_kernel<<<gN, blk, 0, stream>>>(hA, x1, W[1][0], W[1][1], W[1][2], W[1][3], xl, xr, xlh, 25);
    gather_kernel<<<dim3(NB), blk, 0, stream>>>(srt, bstart, xl, xr, xlh, W[1][4], W[1][5], hA);

    // layer 3 (din=25, input [hA, x1])
    prep_kernel<<<gN, blk, 0, stream>>>(hA, x1, W[2][0], W[2][1], W[2][2], W[2][3], xl, xr, xlh, 25);
    gather_kernel<<<dim3(NB), blk, 0, stream>>>(srt, bstart, xl, xr, xlh, W[2][4], W[2][5], hA);

    // heads
    value_kernel<<<gN, blk, 0, stream>>>(hA, x1, x2, lin_W, lin_b, lin2_W, lin2_b, Vsum);
    orders_kernel<<<gT, blk, 0, stream>>>(hA, x1, move_type, m_src, m_dst, m_target,
                                          m_armies, move_id, aaa_W, aaa_b, ccc_W, ccc_b,
                                          attl_W, attl_b, pi_W, pi_b, al, piv, amax);
    orders2_kernel<<<gT, blk, 0, stream>>>(al, piv, move_id, amax, den_m, num_m);
    final_kernel<<<dim3(1), blk, 0, stream>>>(num_m, den_m, Vsum, (float*)d_out);
}

// Round 6
// 526.313 us; speedup vs baseline: 10.5899x; 1.8406x over previous
//
#include <hip/hip_runtime.h>
#include <cmath>

#define NN 100000
#define NE 3200000
#define TT 2048
#define MM 256
#define STR 16    // padded row stride (floats) for 10-wide node arrays -> 64B rows
#define HSTR 16   // row stride (ushorts) for bf16 xl copy -> 32B rows, 3.2MB total (L2-resident)
#define BSZ 64    // nodes per bucket
#define NB 1563   // ceil(NN/BSZ)
#define EPB 8192  // edges per scatter/hist block
#define NBLK 391  // ceil(NE/EPB)
#define SCAP 3072 // in-LDS sort capacity per bucket (mean 2048, sigma ~45 -> 22 sigma headroom)

__device__ __forceinline__ void atomicMaxF(float* addr, float v) {
    if (v >= 0.f) atomicMax((int*)addr, __float_as_int(v));
    else          atomicMin((unsigned int*)addr, __float_as_uint(v));
}

__device__ __forceinline__ unsigned short f2bf(float x) {
    unsigned u = __float_as_uint(x);
    u += 0x7FFFu + ((u >> 16) & 1u);   // round-to-nearest-even
    return (unsigned short)(u >> 16);
}

// ---------------- init: zero bucket counts + small buffers ----------------
__global__ __launch_bounds__(1024) void init_kernel(int* bcounts, float* amax, float* den_m,
                                                    float* num_m, float* Vsum) {
    int i = blockIdx.x * 1024 + threadIdx.x;
    if (i < NB) bcounts[i] = 0;
    if (i < MM) { amax[i] = -INFINITY; den_m[i] = 0.f; num_m[i] = 0.f; }
    if (i == 0) Vsum[0] = 0.f;
}

// ---------------- bucket histogram (LDS pre-aggregated) ----------------
__global__ __launch_bounds__(256) void hist_kernel(const int* __restrict__ dst,
                                                   int* __restrict__ bcounts) {
    __shared__ int h[NB];
    int tid = threadIdx.x;
    for (int i = tid; i < NB; i += 256) h[i] = 0;
    __syncthreads();
    int base = blockIdx.x * EPB;
    int end = base + EPB; if (end > NE) end = NE;
    for (int i = base + tid; i < end; i += 256) atomicAdd(&h[dst[i] >> 6], 1);
    __syncthreads();
    for (int i = tid; i < NB; i += 256) { int n = h[i]; if (n) atomicAdd(&bcounts[i], n); }
}

// ---------------- exclusive scan over NB buckets (single block) ----------------
__global__ __launch_bounds__(1024) void scan_kernel(const int* __restrict__ bcounts,
                                                    int* __restrict__ bstart,
                                                    int* __restrict__ bcursor) {
    __shared__ int ssum[1024];
    int tid = threadIdx.x;
    const int per = (NB + 1023) / 1024;  // 2
    int base = tid * per;
    int s = 0;
    for (int i = 0; i < per; i++) {
        int idx = base + i;
        if (idx < NB) s += bcounts[idx];
    }
    ssum[tid] = s;
    __syncthreads();
    for (int off = 1; off < 1024; off <<= 1) {
        int v = (tid >= off) ? ssum[tid - off] : 0;
        __syncthreads();
        ssum[tid] += v;
        __syncthreads();
    }
    int run = ssum[tid] - s;
    for (int i = 0; i < per; i++) {
        int idx = base + i;
        if (idx < NB) {
            bstart[idx] = run;
            bcursor[idx] = run;
            run += bcounts[idx];
        }
    }
    if (tid == 0) bstart[NB] = NE;
}

// ---------------- scatter: block-aggregated reservations, packed (local_dst,src) -------
__global__ __launch_bounds__(256) void scatter_kernel(const int* __restrict__ src,
                                                      const int* __restrict__ dst,
                                                      int* __restrict__ bcursor,
                                                      int* __restrict__ srt) {
    __shared__ int h[NB];   // local count -> global base
    __shared__ int c[NB];   // local running cursor
    int tid = threadIdx.x;
    for (int i = tid; i < NB; i += 256) h[i] = 0;
    __syncthreads();
    int base = blockIdx.x * EPB;
    int end = base + EPB; if (end > NE) end = NE;
    for (int i = base + tid; i < end; i += 256) atomicAdd(&h[dst[i] >> 6], 1);
    __syncthreads();
    for (int i = tid; i < NB; i += 256) {
        int n = h[i];
        h[i] = n ? atomicAdd(&bcursor[i], n) : 0;
        c[i] = 0;
    }
    __syncthreads();
    for (int i = base + tid; i < end; i += 256) {
        int d = dst[i];
        int b = d >> 6;
        int off = atomicAdd(&c[b], 1);
        srt[h[b] + off] = ((d & 63) << 17) | src[i];
    }
}

// ---------------- one-shot: in-LDS counting sort of each bucket segment by local dst ----
__global__ __launch_bounds__(256) void sort2_kernel(int* __restrict__ srt,
                                                    const int* __restrict__ bstart) {
    __shared__ int ent[SCAP];
    __shared__ int ent2[SCAP];
    __shared__ int cnts[BSZ];
    __shared__ int curs[BSZ];
    int b = blockIdx.x, tid = threadIdx.x;
    int i0 = bstart[b], i1 = bstart[b + 1];
    int cnt = i1 - i0;
    if (cnt > SCAP) cnt = SCAP;   // cannot happen statistically; guard anyway
    if (tid < BSZ) cnts[tid] = 0;
    __syncthreads();
    for (int i = tid; i < cnt; i += 256) {
        int p = srt[i0 + i];
        ent[i] = p;
        atomicAdd(&cnts[p >> 17], 1);
    }
    __syncthreads();
    if (tid == 0) {
        int run = 0;
        for (int k = 0; k < BSZ; k++) { curs[k] = run; run += cnts[k]; }
    }
    __syncthreads();
    for (int i = tid; i < cnt; i += 256) {
        int p = ent[i];
        int pos = atomicAdd(&curs[p >> 17], 1);
        ent2[pos] = p;
    }
    __syncthreads();
    for (int i = tid; i < cnt; i += 256) srt[i0 + i] = ent2[i];
}

// ---------------- per-layer: compute xl (fp32 + bf16 copy), xr ----------------
__global__ __launch_bounds__(256) void prep_kernel(
    const float* __restrict__ hprev,   // [NN,STR] (first 10 cols valid) or nullptr
    const float* __restrict__ x1,      // [NN,15]
    const float* __restrict__ Wl, const float* __restrict__ bl,
    const float* __restrict__ Wr, const float* __restrict__ br,
    float* __restrict__ xl, float* __restrict__ xr,
    unsigned short* __restrict__ xlh,  // [NN,HSTR] bf16 rows (32B stride -> L2-resident)
    int din)                           // 15 or 25
{
    __shared__ float sWl[250], sWr[250], sbl[10], sbr[10];
    int tid = threadIdx.x;
    int nw = 10 * din;
    for (int i = tid; i < nw; i += blockDim.x) { sWl[i] = Wl[i]; sWr[i] = Wr[i]; }
    if (tid < 10) { sbl[tid] = bl[tid]; sbr[tid] = br[tid]; }
    __syncthreads();
    int n = blockIdx.x * blockDim.x + tid;
    if (n >= NN) return;

    float in[25];
    if (din == 15) {
        #pragma unroll
        for (int k = 0; k < 15; k++) in[k] = x1[n * 15 + k];
    } else {
        #pragma unroll
        for (int k = 0; k < 10; k++) in[k] = hprev[n * STR + k];
        #pragma unroll
        for (int k = 0; k < 15; k++) in[10 + k] = x1[n * 15 + k];
    }

    float slv[10];
    #pragma unroll
    for (int j = 0; j < 10; j++) {
        float sl = sbl[j], sr = sbr[j];
        for (int k = 0; k < din; k++) {
            sl += in[k] * sWl[j * din + k];
            sr += in[k] * sWr[j * din + k];
        }
        slv[j] = sl;
        xl[n * STR + j] = sl;
        xr[n * STR + j] = sr;
    }
    // bf16 copy of xl, packed 2 per uint
    unsigned* hp = (unsigned*)(xlh + n * HSTR);
    #pragma unroll
    for (int j = 0; j < 5; j++) {
        unsigned lo = f2bf(slv[2 * j]);
        unsigned hi = f2bf(slv[2 * j + 1]);
        hp[j] = lo | (hi << 16);
    }
}

// ---------------- per-layer: bucket gather, chunked register accumulation ----------
// Edges per bucket are sorted by local dst (sort2), so each lane takes a contiguous
// chunk and accumulates den/acc in REGISTERS, flushing to LDS only on dst change
// (~1.6 lane-atomics/edge instead of 11). Depth-1 software prefetch on the rows.
__global__ __launch_bounds__(256, 4) void gather_kernel(
    const int* __restrict__ srt, const int* __restrict__ bstart,
    const float* __restrict__ xl, const float* __restrict__ xr,
    const unsigned short* __restrict__ xlh,
    const float* __restrict__ att, const float* __restrict__ bias,
    float* __restrict__ hout)
{
    __shared__ float accs[BSZ * 11];  // [local_dst][0..9]=acc, [10]=den
    __shared__ float xrs[BSZ * 11];   // [local_dst][0..9]=xr row
    __shared__ float sat[10];
    int b = blockIdx.x, tid = threadIdx.x;
    if (tid < 10) sat[tid] = att[tid];
    __syncthreads();

    int n0 = b * BSZ;
    if (tid < BSZ) {
        int n = n0 + tid;
        if (n < NN) {
            const float* xln = xl + n * STR;
            const float* xrn = xr + n * STR;
            float a[10], r[10];
            #pragma unroll
            for (int k = 0; k < 10; k++) { a[k] = xln[k]; r[k] = xrn[k]; }
            #pragma unroll
            for (int k = 0; k < 10; k++) xrs[tid * 11 + k] = r[k];
            float e = 0.f;
            #pragma unroll
            for (int k = 0; k < 10; k++) {
                float t = a[k] + r[k];
                t = t > 0.f ? t : 0.2f * t;
                e += sat[k] * t;
            }
            float ex = __expf(e);
            #pragma unroll
            for (int k = 0; k < 10; k++) accs[tid * 11 + k] = ex * a[k];
            accs[tid * 11 + 10] = ex;
        } else {
            #pragma unroll
            for (int k = 0; k < 11; k++) { accs[tid * 11 + k] = 0.f; xrs[tid * 11 + k] = 0.f; }
        }
    }
    __syncthreads();

    int i0 = bstart[b], i1 = bstart[b + 1];
    int cnt = i1 - i0;
    int C = (cnt + 255) >> 8;                 // chunk size per lane (~9)
    int a0 = i0 + tid * C;
    int a1 = a0 + C; if (a1 > i1) a1 = i1;
    if (a0 < a1) {
        int p = srt[a0];
        const unsigned short* row0 = xlh + (p & 0x1FFFF) * HSTR;
        uint4 q = *(const uint4*)row0;
        unsigned q2 = *(const unsigned*)(row0 + 8);
        int cur = p >> 17;
        float racc[10];
        #pragma unroll
        for (int k = 0; k < 10; k++) racc[k] = 0.f;
        float rden = 0.f;
        for (int i = a0; i < a1; i++) {
            // prefetch next edge's row (independent of this iteration's compute)
            int pn = p; uint4 qn = q; unsigned q2n = q2;
            if (i + 1 < a1) {
                pn = srt[i + 1];
                const unsigned short* rn = xlh + (pn & 0x1FFFF) * HSTR;
                qn = *(const uint4*)rn;
                q2n = *(const unsigned*)(rn + 8);
            }
            int ld = p >> 17;
            if (ld != cur) {   // sorted by ld -> flush previous run
                float* ac = accs + cur * 11;
                #pragma unroll
                for (int k = 0; k < 10; k++) atomicAdd(ac + k, racc[k]);
                atomicAdd(ac + 10, rden);
                #pragma unroll
                for (int k = 0; k < 10; k++) racc[k] = 0.f;
                rden = 0.f;
                cur = ld;
            }
            float a[10];
            a[0] = __uint_as_float(q.x << 16);
            a[1] = __uint_as_float(q.x & 0xFFFF0000u);
            a[2] = __uint_as_float(q.y << 16);
            a[3] = __uint_as_float(q.y & 0xFFFF0000u);
            a[4] = __uint_as_float(q.z << 16);
            a[5] = __uint_as_float(q.z & 0xFFFF0000u);
            a[6] = __uint_as_float(q.w << 16);
            a[7] = __uint_as_float(q.w & 0xFFFF0000u);
            a[8] = __uint_as_float(q2 << 16);
            a[9] = __uint_as_float(q2 & 0xFFFF0000u);
            const float* r = xrs + ld * 11;
            float e = 0.f;
            #pragma unroll
            for (int k = 0; k < 10; k++) {
                float t = a[k] + r[k];
                t = t > 0.f ? t : 0.2f * t;
                e += sat[k] * t;
            }
            float ex = __expf(e);
            rden += ex;
            #pragma unroll
            for (int k = 0; k < 10; k++) racc[k] += ex * a[k];
            p = pn; q = qn; q2 = q2n;
        }
        float* ac = accs + cur * 11;
        #pragma unroll
        for (int k = 0; k < 10; k++) atomicAdd(ac + k, racc[k]);
        atomicAdd(ac + 10, rden);
    }
    __syncthreads();

    if (tid < BSZ) {
        int n = n0 + tid;
        if (n < NN) {
            float inv = 1.f / accs[tid * 11 + 10];
            #pragma unroll
            for (int k = 0; k < 10; k++) {
                float v = accs[tid * 11 + k] * inv + bias[k];
                hout[n * STR + k] = v > 0.f ? v : 0.f;
            }
        }
    }
}

// ---------------- value head ----------------
__global__ __launch_bounds__(256) void value_kernel(
    const float* __restrict__ x, const float* __restrict__ x1, const float* __restrict__ x2,
    const float* __restrict__ lin_W, const float* __restrict__ lin_b,
    const float* __restrict__ lin2_W, const float* __restrict__ lin2_b,
    float* __restrict__ Vsum)
{
    __shared__ float sW[15 * 29], sb[15], sW2[15];
    __shared__ float red[256];
    int tid = threadIdx.x;
    for (int i = tid; i < 15 * 29; i += 256) sW[i] = lin_W[i];
    if (tid < 15) { sb[tid] = lin_b[tid]; sW2[tid] = lin2_W[tid]; }
    __syncthreads();
    int n = blockIdx.x * 256 + tid;
    float local = 0.f;
    if (n < NN) {
        float in[29];
        #pragma unroll
        for (int k = 0; k < 10; k++) in[k] = x[n * STR + k];
        #pragma unroll
        for (int k = 0; k < 15; k++) in[10 + k] = x1[n * 15 + k];
        #pragma unroll
        for (int k = 0; k < 4; k++) in[25 + k] = x2[k];
        float sc = lin2_b[0];
        #pragma unroll
        for (int j = 0; j < 15; j++) {
            float s = sb[j];
            for (int k = 0; k < 29; k++) s += in[k] * sW[j * 29 + k];
            sc += (s > 0.f ? s : 0.f) * sW2[j];
        }
        local = sc;
    }
    red[tid] = local;
    __syncthreads();
    for (int off = 128; off > 0; off >>= 1) {
        if (tid < off) red[tid] += red[tid + off];
        __syncthreads();
    }
    if (tid == 0) atomicAdd(Vsum, red[0]);
}

// ---------------- order head, stage 1 ----------------
__global__ __launch_bounds__(256) void orders_kernel(
    const float* __restrict__ x, const float* __restrict__ x1,
    const int* __restrict__ move_type, const int* __restrict__ m_src,
    const int* __restrict__ m_dst, const int* __restrict__ m_target,
    const float* __restrict__ m_armies, const int* __restrict__ move_id,
    const float* __restrict__ aaa_W, const float* __restrict__ aaa_b,
    const float* __restrict__ ccc_W, const float* __restrict__ ccc_b,
    const float* __restrict__ attl_W, const float* __restrict__ attl_b,
    const float* __restrict__ pi_W, const float* __restrict__ pi_b,
    float* __restrict__ al_out, float* __restrict__ pi_out, float* __restrict__ amax)
{
    __shared__ float sA[20 * 48], sC[20 * 23], sAb[20], sCb[20];
    int tid = threadIdx.x;
    for (int i = tid; i < 20 * 48; i += 256) sA[i] = aaa_W[i];
    for (int i = tid; i < 20 * 23; i += 256) sC[i] = ccc_W[i];
    if (tid < 20) { sAb[tid] = aaa_b[tid]; sCb[tid] = ccc_b[tid]; }
    __syncthreads();
    int t = blockIdx.x * 256 + tid;
    if (t >= TT) return;

    float armies = m_armies[t];
    float hm[20];
    if (move_type[t] == 0) {
        int sn = m_src[t], dn = m_dst[t];
        float f[48];
        #pragma unroll
        for (int k = 0; k < 10; k++) f[k] = x[sn * STR + k];
        #pragma unroll
        for (int k = 0; k < 10; k++) f[10 + k] = x[dn * STR + k];
        #pragma unroll
        for (int k = 0; k < 12; k++) f[20 + k] = x1[sn * 15 + 3 + k];
        #pragma unroll
        for (int k = 0; k < 14; k++) f[32 + k] = x1[dn * 15 + 1 + k];
        f[46] = armies;
        f[47] = 0.6f * armies - 0.7f * (x1[dn * 15 + 3] + x1[dn * 15 + 4]);
        #pragma unroll
        for (int j = 0; j < 20; j++) {
            float s = sAb[j];
            for (int k = 0; k < 48; k++) s += f[k] * sA[j * 48 + k];
            hm[j] = s > 0.f ? s : 0.f;
        }
    } else {
        int tg = m_target[t];
        float f[23];
        #pragma unroll
        for (int k = 0; k < 10; k++) f[k] = x[tg * STR + k];
        #pragma unroll
        for (int k = 0; k < 12; k++) f[10 + k] = x1[tg * 15 + 3 + k];
        f[22] = armies;
        #pragma unroll
        for (int j = 0; j < 20; j++) {
            float s = sCb[j];
            for (int k = 0; k < 23; k++) s += f[k] * sC[j * 23 + k];
            hm[j] = s > 0.f ? s : 0.f;
        }
    }
    float a = attl_b[0], p = pi_b[0];
    #pragma unroll
    for (int j = 0; j < 20; j++) { a += hm[j] * attl_W[j]; p += hm[j] * pi_W[j]; }
    al_out[t] = a;
    pi_out[t] = p;
    atomicMaxF(&amax[move_id[t]], a);
}

// ---------------- order head, stage 2 ----------------
__global__ __launch_bounds__(256) void orders2_kernel(
    const float* __restrict__ al, const float* __restrict__ piv,
    const int* __restrict__ move_id, const float* __restrict__ amax,
    float* __restrict__ den_m, float* __restrict__ num_m)
{
    int t = blockIdx.x * 256 + threadIdx.x;
    if (t >= TT) return;
    int m = move_id[t];
    float ex = __expf(al[t] - amax[m]);
    atomicAdd(den_m + m, ex);
    atomicAdd(num_m + m, ex * piv[t]);
}

// ---------------- final: p -> log_softmax, V -> tanh(mean) ----------------
__global__ __launch_bounds__(256) void final_kernel(
    const float* __restrict__ num_m, const float* __restrict__ den_m,
    const float* __restrict__ Vsum, float* __restrict__ out)
{
    __shared__ float sh[256];
    __shared__ float s_max, s_sum;
    int m = threadIdx.x;
    float p = num_m[m] / den_m[m];
    sh[m] = p;
    __syncthreads();
    for (int off = 128; off > 0; off >>= 1) {
        if (m < off) sh[m] = fmaxf(sh[m], sh[m + off]);
        __syncthreads();
    }
    if (m == 0) s_max = sh[0];
    __syncthreads();
    float e = __expf(p - s_max);
    sh[m] = e;
    __syncthreads();
    for (int off = 128; off > 0; off >>= 1) {
        if (m < off) sh[m] += sh[m + off];
        __syncthreads();
    }
    if (m == 0) s_sum = sh[0];
    __syncthreads();
    out[1 + m] = p - s_max - logf(s_sum);
    if (m == 0) out[0] = tanhf(Vsum[0] / (float)NN);
}

extern "C" void kernel_launch(void* const* d_in, const int* in_sizes, int n_in,
                              void* d_out, int out_size, void* d_ws, size_t ws_size,
                              hipStream_t stream) {
    const float* x1        = (const float*)d_in[0];
    const float* x2        = (const float*)d_in[1];
    const int*   esrc      = (const int*)d_in[2];
    const int*   edst      = (const int*)d_in[3];
    const int*   move_type = (const int*)d_in[4];
    const int*   m_src     = (const int*)d_in[5];
    const int*   m_dst     = (const int*)d_in[6];
    const int*   m_target  = (const int*)d_in[7];
    const float* m_armies  = (const float*)d_in[8];
    const int*   move_id   = (const int*)d_in[9];
    const float* W[3][6];
    for (int l = 0; l < 3; l++)
        for (int j = 0; j < 6; j++)
            W[l][j] = (const float*)d_in[10 + l * 6 + j];
    const float* lin_W  = (const float*)d_in[28];
    const float* lin_b  = (const float*)d_in[29];
    const float* lin2_W = (const float*)d_in[30];
    const float* lin2_b = (const float*)d_in[31];
    const float* aaa_W  = (const float*)d_in[32];
    const float* aaa_b  = (const float*)d_in[33];
    const float* ccc_W  = (const float*)d_in[34];
    const float* ccc_b  = (const float*)d_in[35];
    const float* attl_W = (const float*)d_in[36];
    const float* attl_b = (const float*)d_in[37];
    const float* pi_W   = (const float*)d_in[38];
    const float* pi_b   = (const float*)d_in[39];

    // workspace layout (~36 MB)
    float* ws = (float*)d_ws;
    float* xl    = ws; ws += NN * STR;
    float* xr    = ws; ws += NN * STR;
    float* hA    = ws; ws += NN * STR;
    float* al    = ws; ws += TT;
    float* piv   = ws; ws += TT;
    float* amax  = ws; ws += MM;
    float* den_m = ws; ws += MM;
    float* num_m = ws; ws += MM;
    float* Vsum  = ws; ws += 1;
    unsigned short* xlh = (unsigned short*)ws; ws += NN * HSTR / 2;
    int* iws = (int*)ws;
    int* bcounts = iws; iws += NB;
    int* bstart  = iws; iws += NB + 1;
    int* bcursor = iws; iws += NB;
    int* srt     = iws; iws += NE;

    dim3 blk(256);
    dim3 gN((NN + 255) / 256);
    dim3 gT(TT / 256);

    // build bucketed CSR + within-bucket dst sort once; reused by all 3 layers
    init_kernel<<<dim3(2), dim3(1024), 0, stream>>>(bcounts, amax, den_m, num_m, Vsum);
    hist_kernel<<<dim3(NBLK), blk, 0, stream>>>(edst, bcounts);
    scan_kernel<<<dim3(1), dim3(1024), 0, stream>>>(bcounts, bstart, bcursor);
    scatter_kernel<<<dim3(NBLK), blk, 0, stream>>>(esrc, edst, bcursor, srt);
    sort2_kernel<<<dim3(NB), blk, 0, stream>>>(srt, bstart);

    // layer 1 (din=15, input x1)
    prep_kernel<<<gN, blk, 0, stream>>>(nullptr, x1, W[0][0], W[0][1], W[0][2], W[0][3], xl, xr, xlh, 15);
    gather_kernel<<<dim3(NB), blk, 0, stream>>>(srt, bstart, xl, xr, xlh, W[0][4], W[0][5], hA);

    // layer 2 (din=25, input [hA, x1])
    prep_kernel<<<gN, blk, 0, stream>>>(hA, x1, W[1][0], W[1][1], W[1][2], W[1][3], xl, xr, xlh, 25);
    gather_kernel<<<dim3(NB), blk, 0, stream>>>(srt, bstart, xl, xr, xlh, W[1][4], W[1][5], hA);

    // layer 3 (din=25, input [hA, x1])
    prep_kernel<<<gN, blk, 0, stream>>>(hA, x1, W[2][0], W[2][1], W[2][2], W[2][3], xl, xr, xlh, 25);
    gather_kernel<<<dim3(NB), blk, 0, stream>>>(srt, bstart, xl, xr, xlh, W[2][4], W[2][5], hA);

    // heads
    value_kernel<<<gN, blk, 0, stream>>>(hA, x1, x2, lin_W, lin_b, lin2_W, lin2_b, Vsum);
    orders_kernel<<<gT, blk, 0, stream>>>(hA, x1, move_type, m_src, m_dst, m_target,
                                          m_armies, move_id, aaa_W, aaa_b, ccc_W, ccc_b,
                                          attl_W, attl_b, pi_W, pi_b, al, piv, amax);
    orders2_kernel<<<gT, blk, 0, stream>>>(al, piv, move_id, amax, den_m, num_m);
    final_kernel<<<dim3(1), blk, 0, stream>>>(num_m, den_m, Vsum, (float*)d_out);
}